// Round 4
// baseline (651.677 us; speedup 1.0000x reference)
//
#include <hip/hip_runtime.h>

// TransformerWithLocalAttention: B=8, S=4096, D=512, BLOCK=64, window=3 blocks, FF=2048
// Round 4:
//  - attn: 4x parallelism. Block = 16 query rows; 4 waves duplicate QK^T+softmax,
//    each wave does PV for its own 128-dim chunk. Grid (256,8) -> 8192 waves.
//  - gemm: BK=32 triple-buffered LDS (3x32KB), counted vmcnt(4) at tile
//    boundaries (T4); staging for t+2 can never hit a buffer being read.
//    2 phases/tile, T2 both-sides XOR swizzle, T5 setprio, T1 XCD swizzle.

typedef __bf16 bf16;
typedef __bf16 bf16x8 __attribute__((ext_vector_type(8)));
typedef float  f32x4  __attribute__((ext_vector_type(4)));

#define DEV __device__ __forceinline__

#define BAR()  do { asm volatile("" ::: "memory"); __builtin_amdgcn_s_barrier(); asm volatile("" ::: "memory"); } while (0)
#define WAITV(n) asm volatile("s_waitcnt vmcnt(" #n ")" ::: "memory")
#define WAITL()  asm volatile("s_waitcnt lgkmcnt(0)" ::: "memory")

DEV void gload_lds16(const void* g, void* lds) {
  __builtin_amdgcn_global_load_lds(
      (const __attribute__((address_space(1))) void*)g,
      (__attribute__((address_space(3))) void*)lds, 16, 0, 0);
}

// ---------------- elementwise cast x -> bf16 ----------------
__global__ __launch_bounds__(256) void cast_to_bf16(const float* __restrict__ in,
                                                    bf16* __restrict__ out, int n8) {
  int i = blockIdx.x * 256 + threadIdx.x;
  if (i >= n8) return;
  float4 a0 = ((const float4*)in)[i * 2];
  float4 a1 = ((const float4*)in)[i * 2 + 1];
  bf16x8 o;
  o[0] = (bf16)a0.x; o[1] = (bf16)a0.y; o[2] = (bf16)a0.z; o[3] = (bf16)a0.w;
  o[4] = (bf16)a1.x; o[5] = (bf16)a1.y; o[6] = (bf16)a1.z; o[7] = (bf16)a1.w;
  ((bf16x8*)out)[i] = o;
}

// ---------------- W [K][N] f32 -> Wt [N][K] bf16 (LDS-tiled) ----------------
__global__ __launch_bounds__(256) void transpose_cast(const float* __restrict__ W,
                                                      bf16* __restrict__ Wt, int K, int N) {
  __shared__ bf16 tile[64][66];
  const int n0 = blockIdx.x * 64, k0 = blockIdx.y * 64;
  const int t = threadIdx.x;
#pragma unroll
  for (int it = 0; it < 16; ++it) {
    int c = it * 256 + t;
    int kr = c >> 6, nc = c & 63;
    tile[nc][kr] = (bf16)W[(size_t)(k0 + kr) * N + n0 + nc];
  }
  __syncthreads();
#pragma unroll
  for (int it = 0; it < 2; ++it) {
    int c = it * 256 + t;
    int nr = c >> 3, kg = (c & 7) * 8;
    bf16x8 v;
#pragma unroll
    for (int e = 0; e < 8; ++e) v[e] = tile[nr][kg + e];
    *(bf16x8*)(Wt + (size_t)(n0 + nr) * K + k0 + kg) = v;
  }
}

__global__ __launch_bounds__(256) void concat_bias(const float* __restrict__ bq,
                                                   const float* __restrict__ bk,
                                                   const float* __restrict__ bv,
                                                   float* __restrict__ o) {
  int i = blockIdx.x * 256 + threadIdx.x;
  if (i < 512) o[i] = bq[i];
  else if (i < 1024) o[i] = bk[i - 512];
  else if (i < 1536) o[i] = bv[i - 1024];
}

// ---------------- 256x256 GEMM, BK=32, triple-buffered, counted vmcnt --------
// 512 thr = 8 waves (2M x 4N), wave tile 128x64.
// LDS 96KiB: buf t%3 at t%3*32KB = {A[256][32] | B[256][32]} bf16.
// Swizzle: in-row 16B-slot c holds global chunk c ^ (row&3); staged via
// inverse-swizzled GLOBAL source (LDS dest linear), read with the same XOR.
// Tile t: phase0 {8 ds_read (A0-3,B0-3) | stageA(t+2) | bar | lgkm0 | 16 MFMA | bar}
//         phase1 {4 ds_read (A4-7)      | stageB(t+2) | bar | lgkm0 | 16 MFMA}
//         boundary: vmcnt(4) (t+2 in flight) / vmcnt(0) entering last tile; bar.
// Requires NT = K/32 >= 3, M%256==N%256==0, gridDim.x==128.
template <int RELU, int F32OUT>
__global__ __launch_bounds__(512, 1)
void gemm256(const bf16* __restrict__ A, const bf16* __restrict__ Bt,
             const float* __restrict__ bias, void* __restrict__ Cout,
             int M, int N, int K) {
  __shared__ bf16x8 lds8[6144];  // 96 KiB
  char* const LB = (char*)lds8;
  const int tid = threadIdx.x;
  const int w = tid >> 6, l = tid & 63;
  const int lr = l & 15, lg = l >> 4;
  const int wm = w >> 2, wn = w & 3;

  // XCD-aware bijective swizzle (nwg % 8 == 0 for all our grids)
  const int nwg = gridDim.x * gridDim.y;
  const int bid = blockIdx.y * gridDim.x + blockIdx.x;
  const int cpx = nwg >> 3;
  const int swzb = (bid & 7) * cpx + (bid >> 3);
  const int m0 = (swzb & 127) * 256;
  const int n0 = (swzb >> 7) * 256;

  const int NT = K >> 5;

  // staging: thread stages 16B slots tid and tid+512 of a [256][32] tile.
  const int srow = tid >> 2;                         // 0..127 (second load: +128)
  const int scol = (((tid & 3) ^ (srow & 3)) << 3);  // inverse-swizzled col chunk

  // ds_read swizzled slot offset (row&3 == lr&3 for all fragment rows)
  const int swz = ((lg ^ (lr & 3)) << 4);

  f32x4 acc[8][4];
#pragma unroll
  for (int i = 0; i < 8; ++i)
#pragma unroll
    for (int j = 0; j < 4; ++j) acc[i][j] = f32x4{0.f, 0.f, 0.f, 0.f};

  auto stageA = [&](int t) {
    const bf16* g = A + (size_t)(m0 + srow) * K + t * 32 + scol;
    char* d = LB + (t % 3) * 32768 + tid * 16;
    gload_lds16(g, d);
    gload_lds16(g + (size_t)128 * K, d + 8192);
  };
  auto stageB = [&](int t) {
    const bf16* g = Bt + (size_t)(n0 + srow) * K + t * 32 + scol;
    char* d = LB + (t % 3) * 32768 + 16384 + tid * 16;
    gload_lds16(g, d);
    gload_lds16(g + (size_t)128 * K, d + 8192);
  };

  // prologue: tiles 0,1 staged (8 loads); wait tile0 (leave tile1's 4 in flight)
  stageA(0); stageB(0);
  stageA(1); stageB(1);
  WAITV(4);
  BAR();

  for (int t = 0; t < NT; ++t) {
    const char* base = LB + (t % 3) * 32768;
    const char* pA = base + (wm << 13) + lr * 64 + swz;
    const char* pB = base + 16384 + (wn << 12) + lr * 64 + swz;
    bf16x8 a0, a1, a2, a3, b0, b1, b2, b3;
    // ---- phase 0 ----
    a0 = *(const bf16x8*)(pA);
    a1 = *(const bf16x8*)(pA + 1024);
    a2 = *(const bf16x8*)(pA + 2048);
    a3 = *(const bf16x8*)(pA + 3072);
    b0 = *(const bf16x8*)(pB);
    b1 = *(const bf16x8*)(pB + 1024);
    b2 = *(const bf16x8*)(pB + 2048);
    b3 = *(const bf16x8*)(pB + 3072);
    if (t + 2 < NT) stageA(t + 2);
    BAR();
    WAITL();
    __builtin_amdgcn_s_setprio(1);
    acc[0][0] = __builtin_amdgcn_mfma_f32_16x16x32_bf16(a0, b0, acc[0][0], 0, 0, 0);
    acc[0][1] = __builtin_amdgcn_mfma_f32_16x16x32_bf16(a0, b1, acc[0][1], 0, 0, 0);
    acc[0][2] = __builtin_amdgcn_mfma_f32_16x16x32_bf16(a0, b2, acc[0][2], 0, 0, 0);
    acc[0][3] = __builtin_amdgcn_mfma_f32_16x16x32_bf16(a0, b3, acc[0][3], 0, 0, 0);
    acc[1][0] = __builtin_amdgcn_mfma_f32_16x16x32_bf16(a1, b0, acc[1][0], 0, 0, 0);
    acc[1][1] = __builtin_amdgcn_mfma_f32_16x16x32_bf16(a1, b1, acc[1][1], 0, 0, 0);
    acc[1][2] = __builtin_amdgcn_mfma_f32_16x16x32_bf16(a1, b2, acc[1][2], 0, 0, 0);
    acc[1][3] = __builtin_amdgcn_mfma_f32_16x16x32_bf16(a1, b3, acc[1][3], 0, 0, 0);
    acc[2][0] = __builtin_amdgcn_mfma_f32_16x16x32_bf16(a2, b0, acc[2][0], 0, 0, 0);
    acc[2][1] = __builtin_amdgcn_mfma_f32_16x16x32_bf16(a2, b1, acc[2][1], 0, 0, 0);
    acc[2][2] = __builtin_amdgcn_mfma_f32_16x16x32_bf16(a2, b2, acc[2][2], 0, 0, 0);
    acc[2][3] = __builtin_amdgcn_mfma_f32_16x16x32_bf16(a2, b3, acc[2][3], 0, 0, 0);
    acc[3][0] = __builtin_amdgcn_mfma_f32_16x16x32_bf16(a3, b0, acc[3][0], 0, 0, 0);
    acc[3][1] = __builtin_amdgcn_mfma_f32_16x16x32_bf16(a3, b1, acc[3][1], 0, 0, 0);
    acc[3][2] = __builtin_amdgcn_mfma_f32_16x16x32_bf16(a3, b2, acc[3][2], 0, 0, 0);
    acc[3][3] = __builtin_amdgcn_mfma_f32_16x16x32_bf16(a3, b3, acc[3][3], 0, 0, 0);
    __builtin_amdgcn_s_setprio(0);
    BAR();
    // ---- phase 1 ----
    a0 = *(const bf16x8*)(pA + 4096);
    a1 = *(const bf16x8*)(pA + 5120);
    a2 = *(const bf16x8*)(pA + 6144);
    a3 = *(const bf16x8*)(pA + 7168);
    if (t + 2 < NT) stageB(t + 2);
    BAR();
    WAITL();
    __builtin_amdgcn_s_setprio(1);
    acc[4][0] = __builtin_amdgcn_mfma_f32_16x16x32_bf16(a0, b0, acc[4][0], 0, 0, 0);
    acc[4][1] = __builtin_amdgcn_mfma_f32_16x16x32_bf16(a0, b1, acc[4][1], 0, 0, 0);
    acc[4][2] = __builtin_amdgcn_mfma_f32_16x16x32_bf16(a0, b2, acc[4][2], 0, 0, 0);
    acc[4][3] = __builtin_amdgcn_mfma_f32_16x16x32_bf16(a0, b3, acc[4][3], 0, 0, 0);
    acc[5][0] = __builtin_amdgcn_mfma_f32_16x16x32_bf16(a1, b0, acc[5][0], 0, 0, 0);
    acc[5][1] = __builtin_amdgcn_mfma_f32_16x16x32_bf16(a1, b1, acc[5][1], 0, 0, 0);
    acc[5][2] = __builtin_amdgcn_mfma_f32_16x16x32_bf16(a1, b2, acc[5][2], 0, 0, 0);
    acc[5][3] = __builtin_amdgcn_mfma_f32_16x16x32_bf16(a1, b3, acc[5][3], 0, 0, 0);
    acc[6][0] = __builtin_amdgcn_mfma_f32_16x16x32_bf16(a2, b0, acc[6][0], 0, 0, 0);
    acc[6][1] = __builtin_amdgcn_mfma_f32_16x16x32_bf16(a2, b1, acc[6][1], 0, 0, 0);
    acc[6][2] = __builtin_amdgcn_mfma_f32_16x16x32_bf16(a2, b2, acc[6][2], 0, 0, 0);
    acc[6][3] = __builtin_amdgcn_mfma_f32_16x16x32_bf16(a2, b3, acc[6][3], 0, 0, 0);
    acc[7][0] = __builtin_amdgcn_mfma_f32_16x16x32_bf16(a3, b0, acc[7][0], 0, 0, 0);
    acc[7][1] = __builtin_amdgcn_mfma_f32_16x16x32_bf16(a3, b1, acc[7][1], 0, 0, 0);
    acc[7][2] = __builtin_amdgcn_mfma_f32_16x16x32_bf16(a3, b2, acc[7][2], 0, 0, 0);
    acc[7][3] = __builtin_amdgcn_mfma_f32_16x16x32_bf16(a3, b3, acc[7][3], 0, 0, 0);
    __builtin_amdgcn_s_setprio(0);
    // boundary: keep t+2's 4 loads in flight; drain only entering last tile
    if (t + 2 < NT) { WAITV(4); }
    else if (t + 2 == NT) { WAITV(0); }
    BAR();
  }

  // ---- epilogue ----
  if (!F32OUT) {
    // stage C in two 128-row chunks (64KB each) for coalesced 16B stores
    bf16* cl = (bf16*)LB;  // [128][256]
    bf16* Cb = (bf16*)Cout;
#pragma unroll
    for (int half = 0; half < 2; ++half) {
      if (wm == half) {
#pragma unroll
        for (int n = 0; n < 4; ++n) {
          const int col = (wn << 6) + (n << 4) + lr;
          const float bv = bias[n0 + col];
#pragma unroll
          for (int m = 0; m < 8; ++m)
#pragma unroll
            for (int rg = 0; rg < 4; ++rg) {
              const int row = (m << 4) + (lg << 2) + rg;
              float v = acc[m][n][rg] + bv;
              if (RELU) v = fmaxf(v, 0.f);
              cl[row * 256 + col] = (bf16)v;
            }
        }
      }
      __syncthreads();
#pragma unroll
      for (int it = 0; it < 8; ++it) {
        const int idx = it * 512 + tid;
        const int r = idx >> 5, ch = idx & 31;
        *(bf16x8*)(Cb + (size_t)(m0 + half * 128 + r) * N + n0 + (ch << 3)) =
            *(const bf16x8*)(cl + r * 256 + (ch << 3));
      }
      __syncthreads();
    }
  } else {
    // f32 stores: 16 lanes x 4B = 64B contiguous -> already line-coalesced
    float* Cf = (float*)Cout;
#pragma unroll
    for (int n = 0; n < 4; ++n) {
      const int col = n0 + (wn << 6) + (n << 4) + lr;
      const float bv = bias[col];
#pragma unroll
      for (int m = 0; m < 8; ++m)
#pragma unroll
        for (int rg = 0; rg < 4; ++rg) {
          const int row = m0 + (wm << 7) + (m << 4) + (lg << 2) + rg;
          float v = acc[m][n][rg] + bv;
          if (RELU) v = fmaxf(v, 0.f);
          Cf[(size_t)row * N + col] = v;
        }
    }
  }
}

// ---------------- V slice of qkv -> vt [B][512][4096] bf16 ----------------
__global__ __launch_bounds__(256) void transpose_v(const bf16* __restrict__ qkv,
                                                   bf16* __restrict__ vt) {
  __shared__ bf16 tile[64][66];
  const int s0 = blockIdx.x * 64, d0 = blockIdx.y * 64, b = blockIdx.z;
  const int t = threadIdx.x;
#pragma unroll
  for (int it = 0; it < 2; ++it) {
    int c = it * 256 + t;
    int r = c >> 3, g = (c & 7) * 8;
    bf16x8 v = *(const bf16x8*)(qkv + ((size_t)b * 4096 + s0 + r) * 1536 + 1024 + d0 + g);
#pragma unroll
    for (int e = 0; e < 8; ++e) tile[g + e][r] = v[e];
  }
  __syncthreads();
#pragma unroll
  for (int it = 0; it < 2; ++it) {
    int c = it * 256 + t;
    int dr = c >> 3, sg = (c & 7) * 8;
    bf16x8 v;
#pragma unroll
    for (int e = 0; e < 8; ++e) v[e] = tile[dr][sg + e];
    *(bf16x8*)(vt + ((size_t)b * 512 + d0 + dr) * 4096 + s0 + sg) = v;
  }
}

// ---------------- local attention ----------------
// grid (256, 8): blockIdx.x = qb*4 + sub (16 query rows); 4 waves duplicate
// QK^T + softmax for those rows; wave w does PV for dims [w*128, w*128+128).
__global__ __launch_bounds__(256, 6)
void attn_local(const bf16* __restrict__ qkv, const bf16* __restrict__ vt,
                bf16* __restrict__ aout) {
  __shared__ bf16 P[4][16][200];
  const int qb = blockIdx.x >> 2, sub = blockIdx.x & 3, b = blockIdx.y;
  const int t = threadIdx.x, w = t >> 6, l = t & 63;
  const int lr = l & 15, lg = l >> 4;
  const int jlo = (qb == 0) ? 1 : 0;
  const int jhi = (qb == 63) ? 2 : 3;
  const size_t qrow = (size_t)b * 4096 + qb * 64 + sub * 16;
  const bf16* qp = qkv + (qrow + lr) * 1536 + lg * 8;

  f32x4 S[3][4];
#pragma unroll
  for (int j = 0; j < 3; ++j)
#pragma unroll
    for (int n = 0; n < 4; ++n) S[j][n] = f32x4{0.f, 0.f, 0.f, 0.f};

  for (int kk = 0; kk < 16; ++kk) {
    bf16x8 aq = *(const bf16x8*)(qp + kk * 32);
#pragma unroll
    for (int j = 0; j < 3; ++j) {
      if (j < jlo || j >= jhi) continue;
      const bf16* kp = qkv + ((size_t)b * 4096 + (qb - 1 + j) * 64) * 1536 + 512;
#pragma unroll
      for (int n = 0; n < 4; ++n) {
        bf16x8 bk = *(const bf16x8*)(kp + (size_t)(n * 16 + lr) * 1536 + kk * 32 + lg * 8);
        S[j][n] = __builtin_amdgcn_mfma_f32_16x16x32_bf16(aq, bk, S[j][n], 0, 0, 0);
      }
    }
  }

  const float scale = 0.044194173824159216f;  // 1/sqrt(512)
  float mx[4] = {-3e38f, -3e38f, -3e38f, -3e38f};
#pragma unroll
  for (int j = 0; j < 3; ++j) {
    if (j < jlo || j >= jhi) continue;
#pragma unroll
    for (int n = 0; n < 4; ++n)
#pragma unroll
      for (int i = 0; i < 4; ++i) mx[i] = fmaxf(mx[i], S[j][n][i]);
  }
#pragma unroll
  for (int i = 0; i < 4; ++i) {
    mx[i] = fmaxf(mx[i], __shfl_xor(mx[i], 1));
    mx[i] = fmaxf(mx[i], __shfl_xor(mx[i], 2));
    mx[i] = fmaxf(mx[i], __shfl_xor(mx[i], 4));
    mx[i] = fmaxf(mx[i], __shfl_xor(mx[i], 8));
  }
  float sm[4] = {0.f, 0.f, 0.f, 0.f};
#pragma unroll
  for (int j = 0; j < 3; ++j) {
    if (j < jlo || j >= jhi) continue;
#pragma unroll
    for (int n = 0; n < 4; ++n)
#pragma unroll
      for (int i = 0; i < 4; ++i) {
        float p = __expf((S[j][n][i] - mx[i]) * scale);
        S[j][n][i] = p;
        sm[i] += p;
      }
  }
#pragma unroll
  for (int i = 0; i < 4; ++i) {
    sm[i] += __shfl_xor(sm[i], 1);
    sm[i] += __shfl_xor(sm[i], 2);
    sm[i] += __shfl_xor(sm[i], 4);
    sm[i] += __shfl_xor(sm[i], 8);
  }
#pragma unroll
  for (int j = 0; j < 3; ++j) {
    if (j < jlo || j >= jhi) continue;
#pragma unroll
    for (int n = 0; n < 4; ++n)
#pragma unroll
      for (int i = 0; i < 4; ++i)
        P[w][lg * 4 + i][j * 64 + n * 16 + lr] = (bf16)S[j][n][i];
  }
  float rinv[4];
#pragma unroll
  for (int i = 0; i < 4; ++i) rinv[i] = 1.f / sm[i];

  const bf16* vtb = vt + (size_t)b * 512 * 4096;
  const long scol = (long)qb * 64 - 64;

  // PV: this wave's 128-dim chunk only (ch == w)
  f32x4 O[8];
#pragma unroll
  for (int n = 0; n < 8; ++n) O[n] = f32x4{0.f, 0.f, 0.f, 0.f};
#pragma unroll
  for (int j = 0; j < 3; ++j) {
    if (j < jlo || j >= jhi) continue;
#pragma unroll
    for (int k2 = 0; k2 < 2; ++k2) {
      bf16x8 ap = *(const bf16x8*)&P[w][lr][j * 64 + k2 * 32 + lg * 8];
#pragma unroll
      for (int n = 0; n < 8; ++n) {
        const bf16* vp = vtb + (long)(w * 128 + n * 16 + lr) * 4096 +
                         (scol + j * 64 + k2 * 32 + lg * 8);
        bf16x8 bv = *(const bf16x8*)vp;
        O[n] = __builtin_amdgcn_mfma_f32_16x16x32_bf16(ap, bv, O[n], 0, 0, 0);
      }
    }
  }
#pragma unroll
  for (int n = 0; n < 8; ++n)
#pragma unroll
    for (int rg = 0; rg < 4; ++rg) {
      size_t row = qrow + lg * 4 + rg;
      aout[row * 512 + w * 128 + n * 16 + lr] = (bf16)(O[n][rg] * rinv[rg]);
    }
}

// ---------------- LN1: out1 = LN(x + a) -> bf16 ----------------
__global__ __launch_bounds__(256) void ln_res1(const float* __restrict__ x,
                                               const bf16* __restrict__ a,
                                               const float* __restrict__ g,
                                               const float* __restrict__ be,
                                               bf16* __restrict__ out) {
  const int t = threadIdx.x, w = t >> 6, l = t & 63;
  const size_t row = (size_t)blockIdx.x * 4 + w;
  const float* xp = x + row * 512 + l * 8;
  float4 x0 = ((const float4*)xp)[0];
  float4 x1 = ((const float4*)xp)[1];
  bf16x8 av = *(const bf16x8*)(a + row * 512 + l * 8);
  float s[8] = {x0.x + (float)av[0], x0.y + (float)av[1], x0.z + (float)av[2], x0.w + (float)av[3],
                x1.x + (float)av[4], x1.y + (float)av[5], x1.z + (float)av[6], x1.w + (float)av[7]};
  float sum = 0.f;
#pragma unroll
  for (int i = 0; i < 8; ++i) sum += s[i];
#pragma unroll
  for (int m = 1; m <= 32; m <<= 1) sum += __shfl_xor(sum, m);
  const float mean = sum * (1.f / 512.f);
  float vs = 0.f;
#pragma unroll
  for (int i = 0; i < 8; ++i) { float d = s[i] - mean; vs += d * d; }
#pragma unroll
  for (int m = 1; m <= 32; m <<= 1) vs += __shfl_xor(vs, m);
  const float r = rsqrtf(vs * (1.f / 512.f) + 1e-6f);
  float4 g0 = ((const float4*)(g + l * 8))[0], g1 = ((const float4*)(g + l * 8))[1];
  float4 b0 = ((const float4*)(be + l * 8))[0], b1 = ((const float4*)(be + l * 8))[1];
  bf16x8 o;
  o[0] = (bf16)(g0.x * (s[0] - mean) * r + b0.x);
  o[1] = (bf16)(g0.y * (s[1] - mean) * r + b0.y);
  o[2] = (bf16)(g0.z * (s[2] - mean) * r + b0.z);
  o[3] = (bf16)(g0.w * (s[3] - mean) * r + b0.w);
  o[4] = (bf16)(g1.x * (s[4] - mean) * r + b1.x);
  o[5] = (bf16)(g1.y * (s[5] - mean) * r + b1.y);
  o[6] = (bf16)(g1.z * (s[6] - mean) * r + b1.z);
  o[7] = (bf16)(g1.w * (s[7] - mean) * r + b1.w);
  *(bf16x8*)(out + row * 512 + l * 8) = o;
}

// ---------------- LN2: out = LN(out1 + y), y in d_out (f32), in-place ----------------
__global__ __launch_bounds__(256) void ln_res2(const bf16* __restrict__ o1,
                                               float* __restrict__ y,
                                               const float* __restrict__ g,
                                               const float* __restrict__ be) {
  const int t = threadIdx.x, w = t >> 6, l = t & 63;
  const size_t row = (size_t)blockIdx.x * 4 + w;
  float* yp = y + row * 512 + l * 8;
  float4 y0 = ((const float4*)yp)[0];
  float4 y1 = ((const float4*)yp)[1];
  bf16x8 ov = *(const bf16x8*)(o1 + row * 512 + l * 8);
  float s[8] = {y0.x + (float)ov[0], y0.y + (float)ov[1], y0.z + (float)ov[2], y0.w + (float)ov[3],
                y1.x + (float)ov[4], y1.y + (float)ov[5], y1.z + (float)ov[6], y1.w + (float)ov[7]};
  float sum = 0.f;
#pragma unroll
  for (int i = 0; i < 8; ++i) sum += s[i];
#pragma unroll
  for (int m = 1; m <= 32; m <<= 1) sum += __shfl_xor(sum, m);
  const float mean = sum * (1.f / 512.f);
  float vs = 0.f;
#pragma unroll
  for (int i = 0; i < 8; ++i) { float d = s[i] - mean; vs += d * d; }
#pragma unroll
  for (int m = 1; m <= 32; m <<= 1) vs += __shfl_xor(vs, m);
  const float r = rsqrtf(vs * (1.f / 512.f) + 1e-6f);
  float4 g0 = ((const float4*)(g + l * 8))[0], g1 = ((const float4*)(g + l * 8))[1];
  float4 b0 = ((const float4*)(be + l * 8))[0], b1 = ((const float4*)(be + l * 8))[1];
  float4 r0, r1;
  r0.x = g0.x * (s[0] - mean) * r + b0.x;
  r0.y = g0.y * (s[1] - mean) * r + b0.y;
  r0.z = g0.z * (s[2] - mean) * r + b0.z;
  r0.w = g0.w * (s[3] - mean) * r + b0.w;
  r1.x = g1.x * (s[4] - mean) * r + b1.x;
  r1.y = g1.y * (s[5] - mean) * r + b1.y;
  r1.z = g1.z * (s[6] - mean) * r + b1.z;
  r1.w = g1.w * (s[7] - mean) * r + b1.w;
  ((float4*)yp)[0] = r0;
  ((float4*)yp)[1] = r1;
}

extern "C" void kernel_launch(void* const* d_in, const int* in_sizes, int n_in,
                              void* d_out, int out_size, void* d_ws, size_t ws_size,
                              hipStream_t stream) {
  const float* x   = (const float*)d_in[0];
  const float* Wq  = (const float*)d_in[1];
  const float* bq  = (const float*)d_in[2];
  const float* Wk  = (const float*)d_in[3];
  const float* bk  = (const float*)d_in[4];
  const float* Wv  = (const float*)d_in[5];
  const float* bv  = (const float*)d_in[6];
  const float* W1  = (const float*)d_in[7];
  const float* b1  = (const float*)d_in[8];
  const float* W2  = (const float*)d_in[9];
  const float* b2  = (const float*)d_in[10];
  const float* g1  = (const float*)d_in[11];
  const float* be1 = (const float*)d_in[12];
  const float* g2  = (const float*)d_in[13];
  const float* be2 = (const float*)d_in[14];
  float* out = (float*)d_out;

  char* ws = (char*)d_ws;
  // layout (bytes):
  bf16*  WqkvT = (bf16*)(ws + 0);          // [1536][512]      1,572,864
  bf16*  W1T   = (bf16*)(ws + 1572864);    // [2048][512]      2,097,152
  bf16*  W2T   = (bf16*)(ws + 3670016);    // [512][2048]      2,097,152
  float* bqkv  = (float*)(ws + 5767168);   // [1536]           6,144
  bf16*  xb    = (bf16*)(ws + 6291456);    // [32768][512]     33,554,432  (reused as attn out)
  bf16*  out1  = (bf16*)(ws + 39845888);   // [32768][512]     33,554,432
  bf16*  qkv   = (bf16*)(ws + 73400320);   // [32768][1536]    100,663,296
  bf16*  vtb   = (bf16*)(ws + 174063616);  // [8][512][4096]   33,554,432  -> end 207,618,048
  bf16*  a_    = xb;
  // h [32768][2048] bf16 = 134,217,728 B reuses qkv AND vtb regions (both dead
  // by FFN1 time): 73,400,320 + 134,217,728 = 207,618,048 <= ws end.
  bf16*  h     = qkv;

  cast_to_bf16<<<8192, 256, 0, stream>>>(x, xb, 2097152);
  transpose_cast<<<dim3(8, 8), 256, 0, stream>>>(Wq, WqkvT, 512, 512);
  transpose_cast<<<dim3(8, 8), 256, 0, stream>>>(Wk, WqkvT + 262144, 512, 512);
  transpose_cast<<<dim3(8, 8), 256, 0, stream>>>(Wv, WqkvT + 524288, 512, 512);
  transpose_cast<<<dim3(32, 8), 256, 0, stream>>>(W1, W1T, 512, 2048);
  transpose_cast<<<dim3(8, 32), 256, 0, stream>>>(W2, W2T, 2048, 512);
  concat_bias<<<6, 256, 0, stream>>>(bq, bk, bv, bqkv);

  gemm256<0, 0><<<dim3(128, 6), 512, 0, stream>>>(xb, WqkvT, bqkv, qkv, 32768, 1536, 512);
  transpose_v<<<dim3(64, 8, 8), 256, 0, stream>>>(qkv, vtb);
  attn_local<<<dim3(256, 8), 256, 0, stream>>>(qkv, vtb, a_);
  ln_res1<<<8192, 256, 0, stream>>>(x, a_, g1, be1, out1);
  gemm256<1, 0><<<dim3(128, 8), 512, 0, stream>>>(out1, W1T, b1, h, 32768, 2048, 512);
  gemm256<0, 1><<<dim3(128, 2), 512, 0, stream>>>(h, W2T, b2, out, 32768, 512, 2048);
  ln_res2<<<8192, 256, 0, stream>>>(out1, out, g2, be2);
}

// Round 5
// 435.111 us; speedup vs baseline: 1.4977x; 1.4977x over previous
//
#include <hip/hip_runtime.h>

// TransformerWithLocalAttention: B=8, S=4096, D=512, BLOCK=64, window=3 blocks, FF=2048
// Round 5:
//  - attn: grid (64,8) restored (no cross-block K duplication -> FETCH back to
//    ~ideal), 8 waves/block: wave (rg,h) computes QK^T for 16 rows x 96 cols;
//    softmax combined across h-pair via LDS; rinv folded into P; PV split by
//    64-dim chunks per wave (no duplication).
//  - gemm: ONE barrier per K-tile (was 4): {stage(t+2) | 12 ds_read | lgkm |
//    setprio 32 MFMA | vmcnt(4) | bar}. BK=32 triple-buffer counted-vmcnt.

typedef __bf16 bf16;
typedef __bf16 bf16x8 __attribute__((ext_vector_type(8)));
typedef float  f32x4  __attribute__((ext_vector_type(4)));

#define DEV __device__ __forceinline__

#define BAR()  do { asm volatile("" ::: "memory"); __builtin_amdgcn_s_barrier(); asm volatile("" ::: "memory"); } while (0)
#define WAITV(n) asm volatile("s_waitcnt vmcnt(" #n ")" ::: "memory")
#define WAITL()  asm volatile("s_waitcnt lgkmcnt(0)" ::: "memory")

DEV void gload_lds16(const void* g, void* lds) {
  __builtin_amdgcn_global_load_lds(
      (const __attribute__((address_space(1))) void*)g,
      (__attribute__((address_space(3))) void*)lds, 16, 0, 0);
}

// ---------------- elementwise cast x -> bf16 ----------------
__global__ __launch_bounds__(256) void cast_to_bf16(const float* __restrict__ in,
                                                    bf16* __restrict__ out, int n8) {
  int i = blockIdx.x * 256 + threadIdx.x;
  if (i >= n8) return;
  float4 a0 = ((const float4*)in)[i * 2];
  float4 a1 = ((const float4*)in)[i * 2 + 1];
  bf16x8 o;
  o[0] = (bf16)a0.x; o[1] = (bf16)a0.y; o[2] = (bf16)a0.z; o[3] = (bf16)a0.w;
  o[4] = (bf16)a1.x; o[5] = (bf16)a1.y; o[6] = (bf16)a1.z; o[7] = (bf16)a1.w;
  ((bf16x8*)out)[i] = o;
}

// ---------------- W [K][N] f32 -> Wt [N][K] bf16 (LDS-tiled) ----------------
__global__ __launch_bounds__(256) void transpose_cast(const float* __restrict__ W,
                                                      bf16* __restrict__ Wt, int K, int N) {
  __shared__ bf16 tile[64][66];
  const int n0 = blockIdx.x * 64, k0 = blockIdx.y * 64;
  const int t = threadIdx.x;
#pragma unroll
  for (int it = 0; it < 16; ++it) {
    int c = it * 256 + t;
    int kr = c >> 6, nc = c & 63;
    tile[nc][kr] = (bf16)W[(size_t)(k0 + kr) * N + n0 + nc];
  }
  __syncthreads();
#pragma unroll
  for (int it = 0; it < 2; ++it) {
    int c = it * 256 + t;
    int nr = c >> 3, kg = (c & 7) * 8;
    bf16x8 v;
#pragma unroll
    for (int e = 0; e < 8; ++e) v[e] = tile[nr][kg + e];
    *(bf16x8*)(Wt + (size_t)(n0 + nr) * K + k0 + kg) = v;
  }
}

__global__ __launch_bounds__(256) void concat_bias(const float* __restrict__ bq,
                                                   const float* __restrict__ bk,
                                                   const float* __restrict__ bv,
                                                   float* __restrict__ o) {
  int i = blockIdx.x * 256 + threadIdx.x;
  if (i < 512) o[i] = bq[i];
  else if (i < 1024) o[i] = bk[i - 512];
  else if (i < 1536) o[i] = bv[i - 1024];
}

// ---------------- 256x256 GEMM, BK=32, triple-buffered, 1 barrier/tile -------
// 512 thr = 8 waves (2M x 4N), wave tile 128x64.
// LDS 96KiB: buf t%3 = {A[256][32] | B[256][32]} bf16 at t%3*32KB.
// Swizzle: in-row 16B-slot s of row r holds global chunk s^(r&3); staged via
// inverse-swizzled GLOBAL source (LDS dest linear), read with the same XOR.
// Tile t: {stage(t+2) 4 glds | 12 ds_read buf t%3 | lgkm | setprio 32 MFMA |
//          vmcnt(4) (t+2 in flight, t+1 landed) / vmcnt(0) entering last | bar}
template <int RELU, int F32OUT>
__global__ __launch_bounds__(512, 1)
void gemm256(const bf16* __restrict__ A, const bf16* __restrict__ Bt,
             const float* __restrict__ bias, void* __restrict__ Cout,
             int M, int N, int K) {
  __shared__ bf16x8 lds8[6144];  // 96 KiB
  char* const LB = (char*)lds8;
  const int tid = threadIdx.x;
  const int w = tid >> 6, l = tid & 63;
  const int lr = l & 15, lg = l >> 4;
  const int wm = w >> 2, wn = w & 3;

  // XCD-aware bijective swizzle (nwg % 8 == 0 for all our grids)
  const int nwg = gridDim.x * gridDim.y;
  const int bid = blockIdx.y * gridDim.x + blockIdx.x;
  const int cpx = nwg >> 3;
  const int swzb = (bid & 7) * cpx + (bid >> 3);
  const int m0 = (swzb & 127) * 256;
  const int n0 = (swzb >> 7) * 256;

  const int NT = K >> 5;

  const int srow = tid >> 2;                         // 0..127 (second load: +128)
  const int scol = (((tid & 3) ^ (srow & 3)) << 3);  // inverse-swizzled col chunk
  const int swz = ((lg ^ (lr & 3)) << 4);            // ds_read swizzled slot

  f32x4 acc[8][4];
#pragma unroll
  for (int i = 0; i < 8; ++i)
#pragma unroll
    for (int j = 0; j < 4; ++j) acc[i][j] = f32x4{0.f, 0.f, 0.f, 0.f};

  auto stageA = [&](int t) {
    const bf16* g = A + (size_t)(m0 + srow) * K + t * 32 + scol;
    char* d = LB + (t % 3) * 32768 + tid * 16;
    gload_lds16(g, d);
    gload_lds16(g + (size_t)128 * K, d + 8192);
  };
  auto stageB = [&](int t) {
    const bf16* g = Bt + (size_t)(n0 + srow) * K + t * 32 + scol;
    char* d = LB + (t % 3) * 32768 + 16384 + tid * 16;
    gload_lds16(g, d);
    gload_lds16(g + (size_t)128 * K, d + 8192);
  };

  stageA(0); stageB(0);
  stageA(1); stageB(1);
  WAITV(4);
  BAR();

  for (int t = 0; t < NT; ++t) {
    const char* base = LB + (t % 3) * 32768;
    const char* pA = base + (wm << 13) + lr * 64 + swz;
    const char* pB = base + 16384 + (wn << 12) + lr * 64 + swz;
    if (t + 2 < NT) { stageA(t + 2); stageB(t + 2); }
    bf16x8 a0 = *(const bf16x8*)(pA);
    bf16x8 a1 = *(const bf16x8*)(pA + 1024);
    bf16x8 a2 = *(const bf16x8*)(pA + 2048);
    bf16x8 a3 = *(const bf16x8*)(pA + 3072);
    bf16x8 a4 = *(const bf16x8*)(pA + 4096);
    bf16x8 a5 = *(const bf16x8*)(pA + 5120);
    bf16x8 a6 = *(const bf16x8*)(pA + 6144);
    bf16x8 a7 = *(const bf16x8*)(pA + 7168);
    bf16x8 b0 = *(const bf16x8*)(pB);
    bf16x8 b1 = *(const bf16x8*)(pB + 1024);
    bf16x8 b2 = *(const bf16x8*)(pB + 2048);
    bf16x8 b3 = *(const bf16x8*)(pB + 3072);
    WAITL();
    __builtin_amdgcn_s_setprio(1);
    acc[0][0] = __builtin_amdgcn_mfma_f32_16x16x32_bf16(a0, b0, acc[0][0], 0, 0, 0);
    acc[0][1] = __builtin_amdgcn_mfma_f32_16x16x32_bf16(a0, b1, acc[0][1], 0, 0, 0);
    acc[0][2] = __builtin_amdgcn_mfma_f32_16x16x32_bf16(a0, b2, acc[0][2], 0, 0, 0);
    acc[0][3] = __builtin_amdgcn_mfma_f32_16x16x32_bf16(a0, b3, acc[0][3], 0, 0, 0);
    acc[1][0] = __builtin_amdgcn_mfma_f32_16x16x32_bf16(a1, b0, acc[1][0], 0, 0, 0);
    acc[1][1] = __builtin_amdgcn_mfma_f32_16x16x32_bf16(a1, b1, acc[1][1], 0, 0, 0);
    acc[1][2] = __builtin_amdgcn_mfma_f32_16x16x32_bf16(a1, b2, acc[1][2], 0, 0, 0);
    acc[1][3] = __builtin_amdgcn_mfma_f32_16x16x32_bf16(a1, b3, acc[1][3], 0, 0, 0);
    acc[2][0] = __builtin_amdgcn_mfma_f32_16x16x32_bf16(a2, b0, acc[2][0], 0, 0, 0);
    acc[2][1] = __builtin_amdgcn_mfma_f32_16x16x32_bf16(a2, b1, acc[2][1], 0, 0, 0);
    acc[2][2] = __builtin_amdgcn_mfma_f32_16x16x32_bf16(a2, b2, acc[2][2], 0, 0, 0);
    acc[2][3] = __builtin_amdgcn_mfma_f32_16x16x32_bf16(a2, b3, acc[2][3], 0, 0, 0);
    acc[3][0] = __builtin_amdgcn_mfma_f32_16x16x32_bf16(a3, b0, acc[3][0], 0, 0, 0);
    acc[3][1] = __builtin_amdgcn_mfma_f32_16x16x32_bf16(a3, b1, acc[3][1], 0, 0, 0);
    acc[3][2] = __builtin_amdgcn_mfma_f32_16x16x32_bf16(a3, b2, acc[3][2], 0, 0, 0);
    acc[3][3] = __builtin_amdgcn_mfma_f32_16x16x32_bf16(a3, b3, acc[3][3], 0, 0, 0);
    acc[4][0] = __builtin_amdgcn_mfma_f32_16x16x32_bf16(a4, b0, acc[4][0], 0, 0, 0);
    acc[4][1] = __builtin_amdgcn_mfma_f32_16x16x32_bf16(a4, b1, acc[4][1], 0, 0, 0);
    acc[4][2] = __builtin_amdgcn_mfma_f32_16x16x32_bf16(a4, b2, acc[4][2], 0, 0, 0);
    acc[4][3] = __builtin_amdgcn_mfma_f32_16x16x32_bf16(a4, b3, acc[4][3], 0, 0, 0);
    acc[5][0] = __builtin_amdgcn_mfma_f32_16x16x32_bf16(a5, b0, acc[5][0], 0, 0, 0);
    acc[5][1] = __builtin_amdgcn_mfma_f32_16x16x32_bf16(a5, b1, acc[5][1], 0, 0, 0);
    acc[5][2] = __builtin_amdgcn_mfma_f32_16x16x32_bf16(a5, b2, acc[5][2], 0, 0, 0);
    acc[5][3] = __builtin_amdgcn_mfma_f32_16x16x32_bf16(a5, b3, acc[5][3], 0, 0, 0);
    acc[6][0] = __builtin_amdgcn_mfma_f32_16x16x32_bf16(a6, b0, acc[6][0], 0, 0, 0);
    acc[6][1] = __builtin_amdgcn_mfma_f32_16x16x32_bf16(a6, b1, acc[6][1], 0, 0, 0);
    acc[6][2] = __builtin_amdgcn_mfma_f32_16x16x32_bf16(a6, b2, acc[6][2], 0, 0, 0);
    acc[6][3] = __builtin_amdgcn_mfma_f32_16x16x32_bf16(a6, b3, acc[6][3], 0, 0, 0);
    acc[7][0] = __builtin_amdgcn_mfma_f32_16x16x32_bf16(a7, b0, acc[7][0], 0, 0, 0);
    acc[7][1] = __builtin_amdgcn_mfma_f32_16x16x32_bf16(a7, b1, acc[7][1], 0, 0, 0);
    acc[7][2] = __builtin_amdgcn_mfma_f32_16x16x32_bf16(a7, b2, acc[7][2], 0, 0, 0);
    acc[7][3] = __builtin_amdgcn_mfma_f32_16x16x32_bf16(a7, b3, acc[7][3], 0, 0, 0);
    __builtin_amdgcn_s_setprio(0);
    if (t + 2 < NT) { WAITV(4); }
    else if (t + 2 == NT) { WAITV(0); }
    BAR();
  }

  // ---- epilogue ----
  if (!F32OUT) {
    bf16* cl = (bf16*)LB;  // [128][256]
    bf16* Cb = (bf16*)Cout;
#pragma unroll
    for (int half = 0; half < 2; ++half) {
      if (wm == half) {
#pragma unroll
        for (int n = 0; n < 4; ++n) {
          const int col = (wn << 6) + (n << 4) + lr;
          const float bv = bias[n0 + col];
#pragma unroll
          for (int m = 0; m < 8; ++m)
#pragma unroll
            for (int rg = 0; rg < 4; ++rg) {
              const int row = (m << 4) + (lg << 2) + rg;
              float v = acc[m][n][rg] + bv;
              if (RELU) v = fmaxf(v, 0.f);
              cl[row * 256 + col] = (bf16)v;
            }
        }
      }
      __syncthreads();
#pragma unroll
      for (int it = 0; it < 8; ++it) {
        const int idx = it * 512 + tid;
        const int r = idx >> 5, ch = idx & 31;
        *(bf16x8*)(Cb + (size_t)(m0 + half * 128 + r) * N + n0 + (ch << 3)) =
            *(const bf16x8*)(cl + r * 256 + (ch << 3));
      }
      __syncthreads();
    }
  } else {
    float* Cf = (float*)Cout;
#pragma unroll
    for (int n = 0; n < 4; ++n) {
      const int col = n0 + (wn << 6) + (n << 4) + lr;
      const float bv = bias[col];
#pragma unroll
      for (int m = 0; m < 8; ++m)
#pragma unroll
        for (int rg = 0; rg < 4; ++rg) {
          const int row = m0 + (wm << 7) + (m << 4) + (lg << 2) + rg;
          float v = acc[m][n][rg] + bv;
          if (RELU) v = fmaxf(v, 0.f);
          Cf[(size_t)row * N + col] = v;
        }
    }
  }
}

// ---------------- V slice of qkv -> vt [B][512][4096] bf16 ----------------
__global__ __launch_bounds__(256) void transpose_v(const bf16* __restrict__ qkv,
                                                   bf16* __restrict__ vt) {
  __shared__ bf16 tile[64][66];
  const int s0 = blockIdx.x * 64, d0 = blockIdx.y * 64, b = blockIdx.z;
  const int t = threadIdx.x;
#pragma unroll
  for (int it = 0; it < 2; ++it) {
    int c = it * 256 + t;
    int r = c >> 3, g = (c & 7) * 8;
    bf16x8 v = *(const bf16x8*)(qkv + ((size_t)b * 4096 + s0 + r) * 1536 + 1024 + d0 + g);
#pragma unroll
    for (int e = 0; e < 8; ++e) tile[g + e][r] = v[e];
  }
  __syncthreads();
#pragma unroll
  for (int it = 0; it < 2; ++it) {
    int c = it * 256 + t;
    int dr = c >> 3, sg = (c & 7) * 8;
    bf16x8 v;
#pragma unroll
    for (int e = 0; e < 8; ++e) v[e] = tile[dr][sg + e];
    *(bf16x8*)(vt + ((size_t)b * 512 + d0 + dr) * 4096 + s0 + sg) = v;
  }
}

// ---------------- local attention ----------------
// grid (64, 8), 512 threads = 8 waves. Wave (rg = w&3, h = w>>2):
//   QK^T: rows rg*16..rg*16+15, score cols [96h, 96h+96) = n-tiles 6h..6h+5.
//   Softmax combined across the h-pair via LDS; rinv folded into P (bf16).
//   PV: wave w computes all 64 rows x dims [w*64, w*64+64) from P_lds and vt.
__global__ __launch_bounds__(512, 4)
void attn_local(const bf16* __restrict__ qkv, const bf16* __restrict__ vt,
                bf16* __restrict__ aout) {
  __shared__ bf16 P[4][16][200];
  __shared__ float xmx[4][2][16];
  __shared__ float xsm[4][2][16];
  const int qb = blockIdx.x, b = blockIdx.y;
  const int t = threadIdx.x, w = t >> 6, l = t & 63;
  const int rg = w & 3, h = w >> 2;
  const int lr = l & 15, lg = l >> 4;

  bool val[6];
#pragma unroll
  for (int n = 0; n < 6; ++n) {
    int gn = 6 * h + n;
    val[n] = ((unsigned)(qb - 1 + (gn >> 2)) < 64u);
  }

  const size_t qrow = (size_t)b * 4096 + qb * 64 + rg * 16;
  const bf16* qp = qkv + (qrow + lr) * 1536 + lg * 8;
  const bf16* kbase = qkv + ((long)b * 4096 + (long)(qb - 1) * 64) * 1536 + 512;

  f32x4 S[6];
#pragma unroll
  for (int n = 0; n < 6; ++n) S[n] = f32x4{0.f, 0.f, 0.f, 0.f};

  for (int kk = 0; kk < 16; ++kk) {
    bf16x8 aq = *(const bf16x8*)(qp + kk * 32);
#pragma unroll
    for (int n = 0; n < 6; ++n) {
      if (!val[n]) continue;
      const int gn = 6 * h + n;
      bf16x8 bk = *(const bf16x8*)(kbase + (size_t)(gn * 16 + lr) * 1536 + kk * 32 + lg * 8);
      S[n] = __builtin_amdgcn_mfma_f32_16x16x32_bf16(aq, bk, S[n], 0, 0, 0);
    }
  }

  const float scale = 0.044194173824159216f;  // 1/sqrt(512)
  float mx[4] = {-3e38f, -3e38f, -3e38f, -3e38f};
#pragma unroll
  for (int n = 0; n < 6; ++n) {
    if (!val[n]) continue;
#pragma unroll
    for (int i = 0; i < 4; ++i) mx[i] = fmaxf(mx[i], S[n][i]);
  }
#pragma unroll
  for (int i = 0; i < 4; ++i) {
    mx[i] = fmaxf(mx[i], __shfl_xor(mx[i], 1));
    mx[i] = fmaxf(mx[i], __shfl_xor(mx[i], 2));
    mx[i] = fmaxf(mx[i], __shfl_xor(mx[i], 4));
    mx[i] = fmaxf(mx[i], __shfl_xor(mx[i], 8));
  }
  if (lr == 0) {
#pragma unroll
    for (int i = 0; i < 4; ++i) xmx[rg][h][lg * 4 + i] = mx[i];
  }
  __syncthreads();
  float m4[4];
#pragma unroll
  for (int i = 0; i < 4; ++i) m4[i] = fmaxf(mx[i], xmx[rg][h ^ 1][lg * 4 + i]);

  float sm[4] = {0.f, 0.f, 0.f, 0.f};
#pragma unroll
  for (int n = 0; n < 6; ++n) {
    if (!val[n]) continue;
#pragma unroll
    for (int i = 0; i < 4; ++i) {
      float p = __expf((S[n][i] - m4[i]) * scale);
      S[n][i] = p;
      sm[i] += p;
    }
  }
#pragma unroll
  for (int i = 0; i < 4; ++i) {
    sm[i] += __shfl_xor(sm[i], 1);
    sm[i] += __shfl_xor(sm[i], 2);
    sm[i] += __shfl_xor(sm[i], 4);
    sm[i] += __shfl_xor(sm[i], 8);
  }
  if (lr == 0) {
#pragma unroll
    for (int i = 0; i < 4; ++i) xsm[rg][h][lg * 4 + i] = sm[i];
  }
  __syncthreads();
  float rinv[4];
#pragma unroll
  for (int i = 0; i < 4; ++i) rinv[i] = 1.f / (sm[i] + xsm[rg][h ^ 1][lg * 4 + i]);

#pragma unroll
  for (int n = 0; n < 6; ++n) {
    const int gn = 6 * h + n;
#pragma unroll
    for (int i = 0; i < 4; ++i)
      P[rg][lg * 4 + i][gn * 16 + lr] = val[n] ? (bf16)(S[n][i] * rinv[i]) : (bf16)0.f;
  }
  __syncthreads();

  // PV: dims [w*64, w*64+64), all 64 rows
  f32x4 O[4][4];
#pragma unroll
  for (int rt = 0; rt < 4; ++rt)
#pragma unroll
    for (int dt = 0; dt < 4; ++dt) O[rt][dt] = f32x4{0.f, 0.f, 0.f, 0.f};

  const bf16* vtb = vt + ((long)b * 512 + w * 64) * 4096 + (long)(qb - 1) * 64;
#pragma unroll
  for (int ks = 0; ks < 6; ++ks) {
    if ((unsigned)(qb - 1 + (ks >> 1)) >= 64u) continue;
    bf16x8 vf[4];
#pragma unroll
    for (int dt = 0; dt < 4; ++dt)
      vf[dt] = *(const bf16x8*)(vtb + (size_t)(dt * 16 + lr) * 4096 + ks * 32 + lg * 8);
#pragma unroll
    for (int rt = 0; rt < 4; ++rt) {
      bf16x8 pa = *(const bf16x8*)&P[rt][lr][ks * 32 + lg * 8];
#pragma unroll
      for (int dt = 0; dt < 4; ++dt)
        O[rt][dt] = __builtin_amdgcn_mfma_f32_16x16x32_bf16(pa, vf[dt], O[rt][dt], 0, 0, 0);
    }
  }

  const size_t orow = (size_t)b * 4096 + qb * 64;
#pragma unroll
  for (int rt = 0; rt < 4; ++rt)
#pragma unroll
    for (int dt = 0; dt < 4; ++dt)
#pragma unroll
      for (int i = 0; i < 4; ++i)
        aout[(orow + rt * 16 + lg * 4 + i) * 512 + w * 64 + dt * 16 + lr] =
            (bf16)O[rt][dt][i];
}

// ---------------- LN1: out1 = LN(x + a) -> bf16 ----------------
__global__ __launch_bounds__(256) void ln_res1(const float* __restrict__ x,
                                               const bf16* __restrict__ a,
                                               const float* __restrict__ g,
                                               const float* __restrict__ be,
                                               bf16* __restrict__ out) {
  const int t = threadIdx.x, w = t >> 6, l = t & 63;
  const size_t row = (size_t)blockIdx.x * 4 + w;
  const float* xp = x + row * 512 + l * 8;
  float4 x0 = ((const float4*)xp)[0];
  float4 x1 = ((const float4*)xp)[1];
  bf16x8 av = *(const bf16x8*)(a + row * 512 + l * 8);
  float s[8] = {x0.x + (float)av[0], x0.y + (float)av[1], x0.z + (float)av[2], x0.w + (float)av[3],
                x1.x + (float)av[4], x1.y + (float)av[5], x1.z + (float)av[6], x1.w + (float)av[7]};
  float sum = 0.f;
#pragma unroll
  for (int i = 0; i < 8; ++i) sum += s[i];
#pragma unroll
  for (int m = 1; m <= 32; m <<= 1) sum += __shfl_xor(sum, m);
  const float mean = sum * (1.f / 512.f);
  float vs = 0.f;
#pragma unroll
  for (int i = 0; i < 8; ++i) { float d = s[i] - mean; vs += d * d; }
#pragma unroll
  for (int m = 1; m <= 32; m <<= 1) vs += __shfl_xor(vs, m);
  const float r = rsqrtf(vs * (1.f / 512.f) + 1e-6f);
  float4 g0 = ((const float4*)(g + l * 8))[0], g1 = ((const float4*)(g + l * 8))[1];
  float4 b0 = ((const float4*)(be + l * 8))[0], b1 = ((const float4*)(be + l * 8))[1];
  bf16x8 o;
  o[0] = (bf16)(g0.x * (s[0] - mean) * r + b0.x);
  o[1] = (bf16)(g0.y * (s[1] - mean) * r + b0.y);
  o[2] = (bf16)(g0.z * (s[2] - mean) * r + b0.z);
  o[3] = (bf16)(g0.w * (s[3] - mean) * r + b0.w);
  o[4] = (bf16)(g1.x * (s[4] - mean) * r + b1.x);
  o[5] = (bf16)(g1.y * (s[5] - mean) * r + b1.y);
  o[6] = (bf16)(g1.z * (s[6] - mean) * r + b1.z);
  o[7] = (bf16)(g1.w * (s[7] - mean) * r + b1.w);
  *(bf16x8*)(out + row * 512 + l * 8) = o;
}

// ---------------- LN2: out = LN(out1 + y), y in d_out (f32), in-place ----------------
__global__ __launch_bounds__(256) void ln_res2(const bf16* __restrict__ o1,
                                               float* __restrict__ y,
                                               const float* __restrict__ g,
                                               const float* __restrict__ be) {
  const int t = threadIdx.x, w = t >> 6, l = t & 63;
  const size_t row = (size_t)blockIdx.x * 4 + w;
  float* yp = y + row * 512 + l * 8;
  float4 y0 = ((const float4*)yp)[0];
  float4 y1 = ((const float4*)yp)[1];
  bf16x8 ov = *(const bf16x8*)(o1 + row * 512 + l * 8);
  float s[8] = {y0.x + (float)ov[0], y0.y + (float)ov[1], y0.z + (float)ov[2], y0.w + (float)ov[3],
                y1.x + (float)ov[4], y1.y + (float)ov[5], y1.z + (float)ov[6], y1.w + (float)ov[7]};
  float sum = 0.f;
#pragma unroll
  for (int i = 0; i < 8; ++i) sum += s[i];
#pragma unroll
  for (int m = 1; m <= 32; m <<= 1) sum += __shfl_xor(sum, m);
  const float mean = sum * (1.f / 512.f);
  float vs = 0.f;
#pragma unroll
  for (int i = 0; i < 8; ++i) { float d = s[i] - mean; vs += d * d; }
#pragma unroll
  for (int m = 1; m <= 32; m <<= 1) vs += __shfl_xor(vs, m);
  const float r = rsqrtf(vs * (1.f / 512.f) + 1e-6f);
  float4 g0 = ((const float4*)(g + l * 8))[0], g1 = ((const float4*)(g + l * 8))[1];
  float4 b0 = ((const float4*)(be + l * 8))[0], b1 = ((const float4*)(be + l * 8))[1];
  float4 r0, r1;
  r0.x = g0.x * (s[0] - mean) * r + b0.x;
  r0.y = g0.y * (s[1] - mean) * r + b0.y;
  r0.z = g0.z * (s[2] - mean) * r + b0.z;
  r0.w = g0.w * (s[3] - mean) * r + b0.w;
  r1.x = g1.x * (s[4] - mean) * r + b1.x;
  r1.y = g1.y * (s[5] - mean) * r + b1.y;
  r1.z = g1.z * (s[6] - mean) * r + b1.z;
  r1.w = g1.w * (s[7] - mean) * r + b1.w;
  ((float4*)yp)[0] = r0;
  ((float4*)yp)[1] = r1;
}

extern "C" void kernel_launch(void* const* d_in, const int* in_sizes, int n_in,
                              void* d_out, int out_size, void* d_ws, size_t ws_size,
                              hipStream_t stream) {
  const float* x   = (const float*)d_in[0];
  const float* Wq  = (const float*)d_in[1];
  const float* bq  = (const float*)d_in[2];
  const float* Wk  = (const float*)d_in[3];
  const float* bk  = (const float*)d_in[4];
  const float* Wv  = (const float*)d_in[5];
  const float* bv  = (const float*)d_in[6];
  const float* W1  = (const float*)d_in[7];
  const float* b1  = (const float*)d_in[8];
  const float* W2  = (const float*)d_in[9];
  const float* b2  = (const float*)d_in[10];
  const float* g1  = (const float*)d_in[11];
  const float* be1 = (const float*)d_in[12];
  const float* g2  = (const float*)d_in[13];
  const float* be2 = (const float*)d_in[14];
  float* out = (float*)d_out;

  char* ws = (char*)d_ws;
  bf16*  WqkvT = (bf16*)(ws + 0);          // [1536][512]      1,572,864
  bf16*  W1T   = (bf16*)(ws + 1572864);    // [2048][512]      2,097,152
  bf16*  W2T   = (bf16*)(ws + 3670016);    // [512][2048]      2,097,152
  float* bqkv  = (float*)(ws + 5767168);   // [1536]           6,144
  bf16*  xb    = (bf16*)(ws + 6291456);    // [32768][512]     33,554,432  (reused as attn out)
  bf16*  out1  = (bf16*)(ws + 39845888);   // [32768][512]     33,554,432
  bf16*  qkv   = (bf16*)(ws + 73400320);   // [32768][1536]    100,663,296
  bf16*  vtb   = (bf16*)(ws + 174063616);  // [8][512][4096]   33,554,432  -> end 207,618,048
  bf16*  a_    = xb;
  bf16*  h     = qkv;  // h [32768][2048] reuses qkv+vtb (both dead by FFN1)

  cast_to_bf16<<<8192, 256, 0, stream>>>(x, xb, 2097152);
  transpose_cast<<<dim3(8, 8), 256, 0, stream>>>(Wq, WqkvT, 512, 512);
  transpose_cast<<<dim3(8, 8), 256, 0, stream>>>(Wk, WqkvT + 262144, 512, 512);
  transpose_cast<<<dim3(8, 8), 256, 0, stream>>>(Wv, WqkvT + 524288, 512, 512);
  transpose_cast<<<dim3(32, 8), 256, 0, stream>>>(W1, W1T, 512, 2048);
  transpose_cast<<<dim3(8, 32), 256, 0, stream>>>(W2, W2T, 2048, 512);
  concat_bias<<<6, 256, 0, stream>>>(bq, bk, bv, bqkv);

  gemm256<0, 0><<<dim3(128, 6), 512, 0, stream>>>(xb, WqkvT, bqkv, qkv, 32768, 1536, 512);
  transpose_v<<<dim3(64, 8, 8), 256, 0, stream>>>(qkv, vtb);
  attn_local<<<dim3(64, 8), 512, 0, stream>>>(qkv, vtb, a_);
  ln_res1<<<8192, 256, 0, stream>>>(x, a_, g1, be1, out1);
  gemm256<1, 0><<<dim3(128, 8), 512, 0, stream>>>(out1, W1T, b1, h, 32768, 2048, 512);
  gemm256<0, 1><<<dim3(128, 2), 512, 0, stream>>>(h, W2T, b2, out, 32768, 512, 2048);
  ln_res2<<<8192, 256, 0, stream>>>(out1, out, g2, be2);
}

// Round 6
// 413.338 us; speedup vs baseline: 1.5766x; 1.0527x over previous
//
#include <hip/hip_runtime.h>

// TransformerWithLocalAttention: B=8, S=4096, D=512, BLOCK=64, window=3 blocks, FF=2048
// Round 6: GEMM v3. BK=64 (128B LDS rows -> 8-slot XOR swizzle, provably
// conflict-free b128 reads), double-buffered 2x64KB, ONE barrier per K-tile:
// {stage(t+1) -> other buf | 24 ds_read | 64 MFMA | vmcnt(0) | bar}.
// Drain-0 is ~free: issue-to-drain spans the whole ~2500cy tile >> 900cy HBM.
// Double-buffer + 1-tile-ahead staging = WAR race structurally impossible.
// attn (R5 8-wave), LN, transposes unchanged.

typedef __bf16 bf16;
typedef __bf16 bf16x8 __attribute__((ext_vector_type(8)));
typedef float  f32x4  __attribute__((ext_vector_type(4)));

#define DEV __device__ __forceinline__

#define BAR()  do { asm volatile("" ::: "memory"); __builtin_amdgcn_s_barrier(); asm volatile("" ::: "memory"); } while (0)
#define WAITV0() asm volatile("s_waitcnt vmcnt(0)" ::: "memory")

DEV void gload_lds16(const void* g, void* lds) {
  __builtin_amdgcn_global_load_lds(
      (const __attribute__((address_space(1))) void*)g,
      (__attribute__((address_space(3))) void*)lds, 16, 0, 0);
}

// ---------------- elementwise cast x -> bf16 ----------------
__global__ __launch_bounds__(256) void cast_to_bf16(const float* __restrict__ in,
                                                    bf16* __restrict__ out, int n8) {
  int i = blockIdx.x * 256 + threadIdx.x;
  if (i >= n8) return;
  float4 a0 = ((const float4*)in)[i * 2];
  float4 a1 = ((const float4*)in)[i * 2 + 1];
  bf16x8 o;
  o[0] = (bf16)a0.x; o[1] = (bf16)a0.y; o[2] = (bf16)a0.z; o[3] = (bf16)a0.w;
  o[4] = (bf16)a1.x; o[5] = (bf16)a1.y; o[6] = (bf16)a1.z; o[7] = (bf16)a1.w;
  ((bf16x8*)out)[i] = o;
}

// ---------------- W [K][N] f32 -> Wt [N][K] bf16 (LDS-tiled) ----------------
__global__ __launch_bounds__(256) void transpose_cast(const float* __restrict__ W,
                                                      bf16* __restrict__ Wt, int K, int N) {
  __shared__ bf16 tile[64][66];
  const int n0 = blockIdx.x * 64, k0 = blockIdx.y * 64;
  const int t = threadIdx.x;
#pragma unroll
  for (int it = 0; it < 16; ++it) {
    int c = it * 256 + t;
    int kr = c >> 6, nc = c & 63;
    tile[nc][kr] = (bf16)W[(size_t)(k0 + kr) * N + n0 + nc];
  }
  __syncthreads();
#pragma unroll
  for (int it = 0; it < 2; ++it) {
    int c = it * 256 + t;
    int nr = c >> 3, kg = (c & 7) * 8;
    bf16x8 v;
#pragma unroll
    for (int e = 0; e < 8; ++e) v[e] = tile[nr][kg + e];
    *(bf16x8*)(Wt + (size_t)(n0 + nr) * K + k0 + kg) = v;
  }
}

__global__ __launch_bounds__(256) void concat_bias(const float* __restrict__ bq,
                                                   const float* __restrict__ bk,
                                                   const float* __restrict__ bv,
                                                   float* __restrict__ o) {
  int i = blockIdx.x * 256 + threadIdx.x;
  if (i < 512) o[i] = bq[i];
  else if (i < 1024) o[i] = bk[i - 512];
  else if (i < 1536) o[i] = bv[i - 1024];
}

// ---------------- 256x256 GEMM, BK=64, double-buffer, 1 barrier/tile --------
// 512 thr = 8 waves (2M x 4N), wave tile 128x64.
// LDS 128KiB: buf t&1 at (t&1)*64KB = {A[256][64] | B[256][64]} bf16.
// Swizzle: LDS (row r, 16B-slot p) holds global chunk p^(r&7); read of chunk
// c uses p = c^(r&7). 64-lane b128 read: each bank-quad hit by exactly 8
// lanes -> minimum-time, conflict-free.
// Tile t: {stage(t+1) 8 glds -> buf (t+1)&1 | ds_read A/B frags | 64 MFMA |
//          vmcnt(0) | bar}. Requires M%256==N%256==0, K%64==0, gridDim.x==128.
template <int RELU, int F32OUT>
__global__ __launch_bounds__(512, 2)
void gemm256(const bf16* __restrict__ A, const bf16* __restrict__ Bt,
             const float* __restrict__ bias, void* __restrict__ Cout,
             int M, int N, int K) {
  __shared__ bf16x8 lds8[8192];  // 128 KiB
  char* const LB = (char*)lds8;
  const int tid = threadIdx.x;
  const int w = tid >> 6, l = tid & 63;
  const int lr = l & 15, lg = l >> 4;
  const int wm = w >> 2, wn = w & 3;

  // XCD-aware bijective swizzle (nwg % 8 == 0 for all our grids)
  const int nwg = gridDim.x * gridDim.y;
  const int bid = blockIdx.y * gridDim.x + blockIdx.x;
  const int cpx = nwg >> 3;
  const int swzb = (bid & 7) * cpx + (bid >> 3);
  const int m0 = (swzb & 127) * 256;
  const int n0 = (swzb >> 7) * 256;

  const int NT = K >> 6;

  // staging map: sigma = tid + 512*j -> LDS slot sigma (linear), which holds
  // (row = sigma>>3, chunk = (sigma&7) ^ (row&7))
  int srow[4], scol[4];
#pragma unroll
  for (int j = 0; j < 4; ++j) {
    const int sg = tid + 512 * j;
    srow[j] = sg >> 3;
    scol[j] = (((sg & 7) ^ ((sg >> 3) & 7)) << 3);
  }

  // ds_read swizzled slot offsets; row&7 == lr&7 for all fragment rows
  const int swz0 = ((lg ^ (lr & 7)) << 4);          // kk=0 chunks 0..3
  const int swz1 = (((4 | lg) ^ (lr & 7)) << 4);    // kk=1 chunks 4..7

  f32x4 acc[8][4];
#pragma unroll
  for (int i = 0; i < 8; ++i)
#pragma unroll
    for (int j = 0; j < 4; ++j) acc[i][j] = f32x4{0.f, 0.f, 0.f, 0.f};

  auto stage = [&](int t) {
    char* dA = LB + ((t & 1) << 16) + tid * 16;
#pragma unroll
    for (int j = 0; j < 4; ++j) {
      gload_lds16(A + (size_t)(m0 + srow[j]) * K + t * 64 + scol[j], dA + j * 8192);
      gload_lds16(Bt + (size_t)(n0 + srow[j]) * K + t * 64 + scol[j], dA + 32768 + j * 8192);
    }
  };

  stage(0);
  WAITV0();
  BAR();

  for (int t = 0; t < NT; ++t) {
    if (t + 1 < NT) stage(t + 1);
    const char* base = LB + ((t & 1) << 16);
    const char* pA = base + (wm << 14) + (lr << 7);
    const char* pB = base + 32768 + (wn << 13) + (lr << 7);
    bf16x8 bv_[4][2];
#pragma unroll
    for (int n = 0; n < 4; ++n) {
      bv_[n][0] = *(const bf16x8*)(pB + n * 2048 + swz0);
      bv_[n][1] = *(const bf16x8*)(pB + n * 2048 + swz1);
    }
#pragma unroll
    for (int i = 0; i < 8; ++i) {
      bf16x8 a0 = *(const bf16x8*)(pA + i * 2048 + swz0);
      bf16x8 a1 = *(const bf16x8*)(pA + i * 2048 + swz1);
#pragma unroll
      for (int n = 0; n < 4; ++n) {
        acc[i][n] = __builtin_amdgcn_mfma_f32_16x16x32_bf16(a0, bv_[n][0], acc[i][n], 0, 0, 0);
        acc[i][n] = __builtin_amdgcn_mfma_f32_16x16x32_bf16(a1, bv_[n][1], acc[i][n], 0, 0, 0);
      }
    }
    WAITV0();
    BAR();
  }

  // ---- epilogue ----
  if (!F32OUT) {
    bf16* cl = (bf16*)LB;  // [128][256]
    bf16* Cb = (bf16*)Cout;
#pragma unroll
    for (int half = 0; half < 2; ++half) {
      if (wm == half) {
#pragma unroll
        for (int n = 0; n < 4; ++n) {
          const int col = (wn << 6) + (n << 4) + lr;
          const float bv = bias[n0 + col];
#pragma unroll
          for (int m = 0; m < 8; ++m)
#pragma unroll
            for (int rg = 0; rg < 4; ++rg) {
              const int row = (m << 4) + (lg << 2) + rg;
              float v = acc[m][n][rg] + bv;
              if (RELU) v = fmaxf(v, 0.f);
              cl[row * 256 + col] = (bf16)v;
            }
        }
      }
      __syncthreads();
#pragma unroll
      for (int it = 0; it < 8; ++it) {
        const int idx = it * 512 + tid;
        const int r = idx >> 5, ch = idx & 31;
        *(bf16x8*)(Cb + (size_t)(m0 + half * 128 + r) * N + n0 + (ch << 3)) =
            *(const bf16x8*)(cl + r * 256 + (ch << 3));
      }
      __syncthreads();
    }
  } else {
    float* Cf = (float*)Cout;
#pragma unroll
    for (int n = 0; n < 4; ++n) {
      const int col = n0 + (wn << 6) + (n << 4) + lr;
      const float bv = bias[col];
#pragma unroll
      for (int m = 0; m < 8; ++m)
#pragma unroll
        for (int rg = 0; rg < 4; ++rg) {
          const int row = m0 + (wm << 7) + (m << 4) + (lg << 2) + rg;
          float v = acc[m][n][rg] + bv;
          if (RELU) v = fmaxf(v, 0.f);
          Cf[(size_t)row * N + col] = v;
        }
    }
  }
}

// ---------------- V slice of qkv -> vt [B][512][4096] bf16 ----------------
__global__ __launch_bounds__(256) void transpose_v(const bf16* __restrict__ qkv,
                                                   bf16* __restrict__ vt) {
  __shared__ bf16 tile[64][66];
  const int s0 = blockIdx.x * 64, d0 = blockIdx.y * 64, b = blockIdx.z;
  const int t = threadIdx.x;
#pragma unroll
  for (int it = 0; it < 2; ++it) {
    int c = it * 256 + t;
    int r = c >> 3, g = (c & 7) * 8;
    bf16x8 v = *(const bf16x8*)(qkv + ((size_t)b * 4096 + s0 + r) * 1536 + 1024 + d0 + g);
#pragma unroll
    for (int e = 0; e < 8; ++e) tile[g + e][r] = v[e];
  }
  __syncthreads();
#pragma unroll
  for (int it = 0; it < 2; ++it) {
    int c = it * 256 + t;
    int dr = c >> 3, sg = (c & 7) * 8;
    bf16x8 v;
#pragma unroll
    for (int e = 0; e < 8; ++e) v[e] = tile[dr][sg + e];
    *(bf16x8*)(vt + ((size_t)b * 512 + d0 + dr) * 4096 + s0 + sg) = v;
  }
}

// ---------------- local attention ----------------
// grid (64, 8), 512 threads = 8 waves. Wave (rg = w&3, h = w>>2):
//   QK^T: rows rg*16..rg*16+15, score cols [96h, 96h+96) = n-tiles 6h..6h+5.
//   Softmax combined across the h-pair via LDS; rinv folded into P (bf16).
//   PV: wave w computes all 64 rows x dims [w*64, w*64+64) from P_lds and vt.
__global__ __launch_bounds__(512, 4)
void attn_local(const bf16* __restrict__ qkv, const bf16* __restrict__ vt,
                bf16* __restrict__ aout) {
  __shared__ bf16 P[4][16][200];
  __shared__ float xmx[4][2][16];
  __shared__ float xsm[4][2][16];
  const int qb = blockIdx.x, b = blockIdx.y;
  const int t = threadIdx.x, w = t >> 6, l = t & 63;
  const int rg = w & 3, h = w >> 2;
  const int lr = l & 15, lg = l >> 4;

  bool val[6];
#pragma unroll
  for (int n = 0; n < 6; ++n) {
    int gn = 6 * h + n;
    val[n] = ((unsigned)(qb - 1 + (gn >> 2)) < 64u);
  }

  const size_t qrow = (size_t)b * 4096 + qb * 64 + rg * 16;
  const bf16* qp = qkv + (qrow + lr) * 1536 + lg * 8;
  const bf16* kbase = qkv + ((long)b * 4096 + (long)(qb - 1) * 64) * 1536 + 512;

  f32x4 S[6];
#pragma unroll
  for (int n = 0; n < 6; ++n) S[n] = f32x4{0.f, 0.f, 0.f, 0.f};

  for (int kk = 0; kk < 16; ++kk) {
    bf16x8 aq = *(const bf16x8*)(qp + kk * 32);
#pragma unroll
    for (int n = 0; n < 6; ++n) {
      if (!val[n]) continue;
      const int gn = 6 * h + n;
      bf16x8 bk = *(const bf16x8*)(kbase + (size_t)(gn * 16 + lr) * 1536 + kk * 32 + lg * 8);
      S[n] = __builtin_amdgcn_mfma_f32_16x16x32_bf16(aq, bk, S[n], 0, 0, 0);
    }
  }

  const float scale = 0.044194173824159216f;  // 1/sqrt(512)
  float mx[4] = {-3e38f, -3e38f, -3e38f, -3e38f};
#pragma unroll
  for (int n = 0; n < 6; ++n) {
    if (!val[n]) continue;
#pragma unroll
    for (int i = 0; i < 4; ++i) mx[i] = fmaxf(mx[i], S[n][i]);
  }
#pragma unroll
  for (int i = 0; i < 4; ++i) {
    mx[i] = fmaxf(mx[i], __shfl_xor(mx[i], 1));
    mx[i] = fmaxf(mx[i], __shfl_xor(mx[i], 2));
    mx[i] = fmaxf(mx[i], __shfl_xor(mx[i], 4));
    mx[i] = fmaxf(mx[i], __shfl_xor(mx[i], 8));
  }
  if (lr == 0) {
#pragma unroll
    for (int i = 0; i < 4; ++i) xmx[rg][h][lg * 4 + i] = mx[i];
  }
  __syncthreads();
  float m4[4];
#pragma unroll
  for (int i = 0; i < 4; ++i) m4[i] = fmaxf(mx[i], xmx[rg][h ^ 1][lg * 4 + i]);

  float sm[4] = {0.f, 0.f, 0.f, 0.f};
#pragma unroll
  for (int n = 0; n < 6; ++n) {
    if (!val[n]) continue;
#pragma unroll
    for (int i = 0; i < 4; ++i) {
      float p = __expf((S[n][i] - m4[i]) * scale);
      S[n][i] = p;
      sm[i] += p;
    }
  }
#pragma unroll
  for (int i = 0; i < 4; ++i) {
    sm[i] += __shfl_xor(sm[i], 1);
    sm[i] += __shfl_xor(sm[i], 2);
    sm[i] += __shfl_xor(sm[i], 4);
    sm[i] += __shfl_xor(sm[i], 8);
  }
  if (lr == 0) {
#pragma unroll
    for (int i = 0; i < 4; ++i) xsm[rg][h][lg * 4 + i] = sm[i];
  }
  __syncthreads();
  float rinv[4];
#pragma unroll
  for (int i = 0; i < 4; ++i) rinv[i] = 1.f / (sm[i] + xsm[rg][h ^ 1][lg * 4 + i]);

#pragma unroll
  for (int n = 0; n < 6; ++n) {
    const int gn = 6 * h + n;
#pragma unroll
    for (int i = 0; i < 4; ++i)
      P[rg][lg * 4 + i][gn * 16 + lr] = val[n] ? (bf16)(S[n][i] * rinv[i]) : (bf16)0.f;
  }
  __syncthreads();

  // PV: dims [w*64, w*64+64), all 64 rows
  f32x4 O[4][4];
#pragma unroll
  for (int rt = 0; rt < 4; ++rt)
#pragma unroll
    for (int dt = 0; dt < 4; ++dt) O[rt][dt] = f32x4{0.f, 0.f, 0.f, 0.f};

  const bf16* vtb = vt + ((long)b * 512 + w * 64) * 4096 + (long)(qb - 1) * 64;
#pragma unroll
  for (int ks = 0; ks < 6; ++ks) {
    if ((unsigned)(qb - 1 + (ks >> 1)) >= 64u) continue;
    bf16x8 vf[4];
#pragma unroll
    for (int dt = 0; dt < 4; ++dt)
      vf[dt] = *(const bf16x8*)(vtb + (size_t)(dt * 16 + lr) * 4096 + ks * 32 + lg * 8);
#pragma unroll
    for (int rt = 0; rt < 4; ++rt) {
      bf16x8 pa = *(const bf16x8*)&P[rt][lr][ks * 32 + lg * 8];
#pragma unroll
      for (int dt = 0; dt < 4; ++dt)
        O[rt][dt] = __builtin_amdgcn_mfma_f32_16x16x32_bf16(pa, vf[dt], O[rt][dt], 0, 0, 0);
    }
  }

  const size_t orow = (size_t)b * 4096 + qb * 64;
#pragma unroll
  for (int rt = 0; rt < 4; ++rt)
#pragma unroll
    for (int dt = 0; dt < 4; ++dt)
#pragma unroll
      for (int i = 0; i < 4; ++i)
        aout[(orow + rt * 16 + lg * 4 + i) * 512 + w * 64 + dt * 16 + lr] =
            (bf16)O[rt][dt][i];
}

// ---------------- LN1: out1 = LN(x + a) -> bf16 ----------------
__global__ __launch_bounds__(256) void ln_res1(const float* __restrict__ x,
                                               const bf16* __restrict__ a,
                                               const float* __restrict__ g,
                                               const float* __restrict__ be,
                                               bf16* __restrict__ out) {
  const int t = threadIdx.x, w = t >> 6, l = t & 63;
  const size_t row = (size_t)blockIdx.x * 4 + w;
  const float* xp = x + row * 512 + l * 8;
  float4 x0 = ((const float4*)xp)[0];
  float4 x1 = ((const float4*)xp)[1];
  bf16x8 av = *(const bf16x8*)(a + row * 512 + l * 8);
  float s[8] = {x0.x + (float)av[0], x0.y + (float)av[1], x0.z + (float)av[2], x0.w + (float)av[3],
                x1.x + (float)av[4], x1.y + (float)av[5], x1.z + (float)av[6], x1.w + (float)av[7]};
  float sum = 0.f;
#pragma unroll
  for (int i = 0; i < 8; ++i) sum += s[i];
#pragma unroll
  for (int m = 1; m <= 32; m <<= 1) sum += __shfl_xor(sum, m);
  const float mean = sum * (1.f / 512.f);
  float vs = 0.f;
#pragma unroll
  for (int i = 0; i < 8; ++i) { float d = s[i] - mean; vs += d * d; }
#pragma unroll
  for (int m = 1; m <= 32; m <<= 1) vs += __shfl_xor(vs, m);
  const float r = rsqrtf(vs * (1.f / 512.f) + 1e-6f);
  float4 g0 = ((const float4*)(g + l * 8))[0], g1 = ((const float4*)(g + l * 8))[1];
  float4 b0 = ((const float4*)(be + l * 8))[0], b1 = ((const float4*)(be + l * 8))[1];
  bf16x8 o;
  o[0] = (bf16)(g0.x * (s[0] - mean) * r + b0.x);
  o[1] = (bf16)(g0.y * (s[1] - mean) * r + b0.y);
  o[2] = (bf16)(g0.z * (s[2] - mean) * r + b0.z);
  o[3] = (bf16)(g0.w * (s[3] - mean) * r + b0.w);
  o[4] = (bf16)(g1.x * (s[4] - mean) * r + b1.x);
  o[5] = (bf16)(g1.y * (s[5] - mean) * r + b1.y);
  o[6] = (bf16)(g1.z * (s[6] - mean) * r + b1.z);
  o[7] = (bf16)(g1.w * (s[7] - mean) * r + b1.w);
  *(bf16x8*)(out + row * 512 + l * 8) = o;
}

// ---------------- LN2: out = LN(out1 + y), y in d_out (f32), in-place ----------------
__global__ __launch_bounds__(256) void ln_res2(const bf16* __restrict__ o1,
                                               float* __restrict__ y,
                                               const float* __restrict__ g,
                                               const float* __restrict__ be) {
  const int t = threadIdx.x, w = t >> 6, l = t & 63;
  const size_t row = (size_t)blockIdx.x * 4 + w;
  float* yp = y + row * 512 + l * 8;
  float4 y0 = ((const float4*)yp)[0];
  float4 y1 = ((const float4*)yp)[1];
  bf16x8 ov = *(const bf16x8*)(o1 + row * 512 + l * 8);
  float s[8] = {y0.x + (float)ov[0], y0.y + (float)ov[1], y0.z + (float)ov[2], y0.w + (float)ov[3],
                y1.x + (float)ov[4], y1.y + (float)ov[5], y1.z + (float)ov[6], y1.w + (float)ov[7]};
  float sum = 0.f;
#pragma unroll
  for (int i = 0; i < 8; ++i) sum += s[i];
#pragma unroll
  for (int m = 1; m <= 32; m <<= 1) sum += __shfl_xor(sum, m);
  const float mean = sum * (1.f / 512.f);
  float vs = 0.f;
#pragma unroll
  for (int i = 0; i < 8; ++i) { float d = s[i] - mean; vs += d * d; }
#pragma unroll
  for (int m = 1; m <= 32; m <<= 1) vs += __shfl_xor(vs, m);
  const float r = rsqrtf(vs * (1.f / 512.f) + 1e-6f);
  float4 g0 = ((const float4*)(g + l * 8))[0], g1 = ((const float4*)(g + l * 8))[1];
  float4 b0 = ((const float4*)(be + l * 8))[0], b1 = ((const float4*)(be + l * 8))[1];
  float4 r0, r1;
  r0.x = g0.x * (s[0] - mean) * r + b0.x;
  r0.y = g0.y * (s[1] - mean) * r + b0.y;
  r0.z = g0.z * (s[2] - mean) * r + b0.z;
  r0.w = g0.w * (s[3] - mean) * r + b0.w;
  r1.x = g1.x * (s[4] - mean) * r + b1.x;
  r1.y = g1.y * (s[5] - mean) * r + b1.y;
  r1.z = g1.z * (s[6] - mean) * r + b1.z;
  r1.w = g1.w * (s[7] - mean) * r + b1.w;
  ((float4*)yp)[0] = r0;
  ((float4*)yp)[1] = r1;
}

extern "C" void kernel_launch(void* const* d_in, const int* in_sizes, int n_in,
                              void* d_out, int out_size, void* d_ws, size_t ws_size,
                              hipStream_t stream) {
  const float* x   = (const float*)d_in[0];
  const float* Wq  = (const float*)d_in[1];
  const float* bq  = (const float*)d_in[2];
  const float* Wk  = (const float*)d_in[3];
  const float* bk  = (const float*)d_in[4];
  const float* Wv  = (const float*)d_in[5];
  const float* bv  = (const float*)d_in[6];
  const float* W1  = (const float*)d_in[7];
  const float* b1  = (const float*)d_in[8];
  const float* W2  = (const float*)d_in[9];
  const float* b2  = (const float*)d_in[10];
  const float* g1  = (const float*)d_in[11];
  const float* be1 = (const float*)d_in[12];
  const float* g2  = (const float*)d_in[13];
  const float* be2 = (const float*)d_in[14];
  float* out = (float*)d_out;

  char* ws = (char*)d_ws;
  bf16*  WqkvT = (bf16*)(ws + 0);          // [1536][512]      1,572,864
  bf16*  W1T   = (bf16*)(ws + 1572864);    // [2048][512]      2,097,152
  bf16*  W2T   = (bf16*)(ws + 3670016);    // [512][2048]      2,097,152
  float* bqkv  = (float*)(ws + 5767168);   // [1536]           6,144
  bf16*  xb    = (bf16*)(ws + 6291456);    // [32768][512]     33,554,432  (reused as attn out)
  bf16*  out1  = (bf16*)(ws + 39845888);   // [32768][512]     33,554,432
  bf16*  qkv   = (bf16*)(ws + 73400320);   // [32768][1536]    100,663,296
  bf16*  vtb   = (bf16*)(ws + 174063616);  // [8][512][4096]   33,554,432  -> end 207,618,048
  bf16*  a_    = xb;
  bf16*  h     = qkv;  // h [32768][2048] reuses qkv+vtb (both dead by FFN1)

  cast_to_bf16<<<8192, 256, 0, stream>>>(x, xb, 2097152);
  transpose_cast<<<dim3(8, 8), 256, 0, stream>>>(Wq, WqkvT, 512, 512);
  transpose_cast<<<dim3(8, 8), 256, 0, stream>>>(Wk, WqkvT + 262144, 512, 512);
  transpose_cast<<<dim3(8, 8), 256, 0, stream>>>(Wv, WqkvT + 524288, 512, 512);
  transpose_cast<<<dim3(32, 8), 256, 0, stream>>>(W1, W1T, 512, 2048);
  transpose_cast<<<dim3(8, 32), 256, 0, stream>>>(W2, W2T, 2048, 512);
  concat_bias<<<6, 256, 0, stream>>>(bq, bk, bv, bqkv);

  gemm256<0, 0><<<dim3(128, 6), 512, 0, stream>>>(xb, WqkvT, bqkv, qkv, 32768, 1536, 512);
  transpose_v<<<dim3(64, 8, 8), 256, 0, stream>>>(qkv, vtb);
  attn_local<<<dim3(64, 8), 512, 0, stream>>>(qkv, vtb, a_);
  ln_res1<<<8192, 256, 0, stream>>>(x, a_, g1, be1, out1);
  gemm256<1, 0><<<dim3(128, 8), 512, 0, stream>>>(out1, W1T, b1, h, 32768, 2048, 512);
  gemm256<0, 1><<<dim3(128, 2), 512, 0, stream>>>(h, W2T, b2, out, 32768, 512, 2048);
  ln_res2<<<8192, 256, 0, stream>>>(out1, out, g2, be2);
}

// Round 7
// 401.657 us; speedup vs baseline: 1.6225x; 1.0291x over previous
//
#include <hip/hip_runtime.h>

// TransformerWithLocalAttention: B=8, S=4096, D=512, BLOCK=64, window=3 blocks, FF=2048
// Round 7: GEMM dispatch remap for L2 locality. Each XCD owns an m-slice
// (16 of 128 m-tiles), n-fastest within the slice -> per-XCD concurrent
// working set (A-slice ~1MB + all B panels <=2MB) fits the 4MB XCD L2; A is
// fetched from HBM ~once instead of once per n-group. Also: epilogue C-stage
// LDS padded to 264 bf16/row (breaks 128B bank period). K-loop unchanged
// (BK=64, 128B-row XOR swizzle, double-buffer, 1 barrier/tile).

typedef __bf16 bf16;
typedef __bf16 bf16x8 __attribute__((ext_vector_type(8)));
typedef float  f32x4  __attribute__((ext_vector_type(4)));

#define DEV __device__ __forceinline__

#define BAR()  do { asm volatile("" ::: "memory"); __builtin_amdgcn_s_barrier(); asm volatile("" ::: "memory"); } while (0)
#define WAITV0() asm volatile("s_waitcnt vmcnt(0)" ::: "memory")

DEV void gload_lds16(const void* g, void* lds) {
  __builtin_amdgcn_global_load_lds(
      (const __attribute__((address_space(1))) void*)g,
      (__attribute__((address_space(3))) void*)lds, 16, 0, 0);
}

// ---------------- elementwise cast x -> bf16 ----------------
__global__ __launch_bounds__(256) void cast_to_bf16(const float* __restrict__ in,
                                                    bf16* __restrict__ out, int n8) {
  int i = blockIdx.x * 256 + threadIdx.x;
  if (i >= n8) return;
  float4 a0 = ((const float4*)in)[i * 2];
  float4 a1 = ((const float4*)in)[i * 2 + 1];
  bf16x8 o;
  o[0] = (bf16)a0.x; o[1] = (bf16)a0.y; o[2] = (bf16)a0.z; o[3] = (bf16)a0.w;
  o[4] = (bf16)a1.x; o[5] = (bf16)a1.y; o[6] = (bf16)a1.z; o[7] = (bf16)a1.w;
  ((bf16x8*)out)[i] = o;
}

// ---------------- W [K][N] f32 -> Wt [N][K] bf16 (LDS-tiled) ----------------
__global__ __launch_bounds__(256) void transpose_cast(const float* __restrict__ W,
                                                      bf16* __restrict__ Wt, int K, int N) {
  __shared__ bf16 tile[64][66];
  const int n0 = blockIdx.x * 64, k0 = blockIdx.y * 64;
  const int t = threadIdx.x;
#pragma unroll
  for (int it = 0; it < 16; ++it) {
    int c = it * 256 + t;
    int kr = c >> 6, nc = c & 63;
    tile[nc][kr] = (bf16)W[(size_t)(k0 + kr) * N + n0 + nc];
  }
  __syncthreads();
#pragma unroll
  for (int it = 0; it < 2; ++it) {
    int c = it * 256 + t;
    int nr = c >> 3, kg = (c & 7) * 8;
    bf16x8 v;
#pragma unroll
    for (int e = 0; e < 8; ++e) v[e] = tile[nr][kg + e];
    *(bf16x8*)(Wt + (size_t)(n0 + nr) * K + k0 + kg) = v;
  }
}

__global__ __launch_bounds__(256) void concat_bias(const float* __restrict__ bq,
                                                   const float* __restrict__ bk,
                                                   const float* __restrict__ bv,
                                                   float* __restrict__ o) {
  int i = blockIdx.x * 256 + threadIdx.x;
  if (i < 512) o[i] = bq[i];
  else if (i < 1024) o[i] = bk[i - 512];
  else if (i < 1536) o[i] = bv[i - 1024];
}

// ---------------- 256x256 GEMM, BK=64, double-buffer, 1 barrier/tile --------
// 512 thr = 8 waves (2M x 4N), wave tile 128x64.
// LDS 128KiB: buf t&1 at (t&1)*64KB = {A[256][64] | B[256][64]} bf16.
// Swizzle: LDS (row r, 16B-slot p) holds global chunk p^(r&7).
// Dispatch: xcd = bid&7 owns m-tiles [xcd*16, xcd*16+16), n-fastest.
// Requires M == 32768 (128 m-tiles), N%256==0, K%64==0, gridDim.x==128.
template <int RELU, int F32OUT>
__global__ __launch_bounds__(512, 2)
void gemm256(const bf16* __restrict__ A, const bf16* __restrict__ Bt,
             const float* __restrict__ bias, void* __restrict__ Cout,
             int M, int N, int K) {
  __shared__ bf16x8 lds8[8192];  // 128 KiB
  char* const LB = (char*)lds8;
  const int tid = threadIdx.x;
  const int w = tid >> 6, l = tid & 63;
  const int lr = l & 15, lg = l >> 4;
  const int wm = w >> 2, wn = w & 3;

  // XCD-locality remap: each XCD owns an m-slice; n varies fastest so
  // consecutive blocks share the A-tile and cycle B panels (all L2-resident).
  const int bid = blockIdx.y * gridDim.x + blockIdx.x;
  const int NX = gridDim.y;
  const int xcd = bid & 7;
  const int idx = bid >> 3;
  const int mi = idx / NX;         // 0..15
  const int nn = idx - mi * NX;    // 0..NX-1
  const int m0 = (xcd * 16 + mi) * 256;
  const int n0 = nn * 256;

  const int NT = K >> 6;

  // staging map: slot sigma = tid + 512*j holds (row sigma>>3, chunk (sigma&7)^(row&7))
  int srow[4], scol[4];
#pragma unroll
  for (int j = 0; j < 4; ++j) {
    const int sg = tid + 512 * j;
    srow[j] = sg >> 3;
    scol[j] = (((sg & 7) ^ ((sg >> 3) & 7)) << 3);
  }

  // ds_read swizzled slot offsets; row&7 == lr&7 for all fragment rows
  const int swz0 = ((lg ^ (lr & 7)) << 4);          // kk=0 chunks 0..3
  const int swz1 = (((4 | lg) ^ (lr & 7)) << 4);    // kk=1 chunks 4..7

  f32x4 acc[8][4];
#pragma unroll
  for (int i = 0; i < 8; ++i)
#pragma unroll
    for (int j = 0; j < 4; ++j) acc[i][j] = f32x4{0.f, 0.f, 0.f, 0.f};

  auto stage = [&](int t) {
    char* dA = LB + ((t & 1) << 16) + tid * 16;
#pragma unroll
    for (int j = 0; j < 4; ++j) {
      gload_lds16(A + (size_t)(m0 + srow[j]) * K + t * 64 + scol[j], dA + j * 8192);
      gload_lds16(Bt + (size_t)(n0 + srow[j]) * K + t * 64 + scol[j], dA + 32768 + j * 8192);
    }
  };

  stage(0);
  WAITV0();
  BAR();

  for (int t = 0; t < NT; ++t) {
    if (t + 1 < NT) stage(t + 1);
    const char* base = LB + ((t & 1) << 16);
    const char* pA = base + (wm << 14) + (lr << 7);
    const char* pB = base + 32768 + (wn << 13) + (lr << 7);
    bf16x8 bv_[4][2];
#pragma unroll
    for (int n = 0; n < 4; ++n) {
      bv_[n][0] = *(const bf16x8*)(pB + n * 2048 + swz0);
      bv_[n][1] = *(const bf16x8*)(pB + n * 2048 + swz1);
    }
#pragma unroll
    for (int i = 0; i < 8; ++i) {
      bf16x8 a0 = *(const bf16x8*)(pA + i * 2048 + swz0);
      bf16x8 a1 = *(const bf16x8*)(pA + i * 2048 + swz1);
#pragma unroll
      for (int n = 0; n < 4; ++n) {
        acc[i][n] = __builtin_amdgcn_mfma_f32_16x16x32_bf16(a0, bv_[n][0], acc[i][n], 0, 0, 0);
        acc[i][n] = __builtin_amdgcn_mfma_f32_16x16x32_bf16(a1, bv_[n][1], acc[i][n], 0, 0, 0);
      }
    }
    WAITV0();
    BAR();
  }

  // ---- epilogue ----
  if (!F32OUT) {
    // C-stage rows padded to 264 bf16 (528B != 128B bank period)
    bf16* cl = (bf16*)LB;  // [128][264]
    bf16* Cb = (bf16*)Cout;
#pragma unroll
    for (int half = 0; half < 2; ++half) {
      if (wm == half) {
#pragma unroll
        for (int n = 0; n < 4; ++n) {
          const int col = (wn << 6) + (n << 4) + lr;
          const float bv = bias[n0 + col];
#pragma unroll
          for (int m = 0; m < 8; ++m)
#pragma unroll
            for (int rg = 0; rg < 4; ++rg) {
              const int row = (m << 4) + (lg << 2) + rg;
              float v = acc[m][n][rg] + bv;
              if (RELU) v = fmaxf(v, 0.f);
              cl[row * 264 + col] = (bf16)v;
            }
        }
      }
      __syncthreads();
#pragma unroll
      for (int it = 0; it < 8; ++it) {
        const int idx2 = it * 512 + tid;
        const int r = idx2 >> 5, ch = idx2 & 31;
        *(bf16x8*)(Cb + (size_t)(m0 + half * 128 + r) * N + n0 + (ch << 3)) =
            *(const bf16x8*)(cl + r * 264 + (ch << 3));
      }
      __syncthreads();
    }
  } else {
    float* Cf = (float*)Cout;
#pragma unroll
    for (int n = 0; n < 4; ++n) {
      const int col = n0 + (wn << 6) + (n << 4) + lr;
      const float bv = bias[col];
#pragma unroll
      for (int m = 0; m < 8; ++m)
#pragma unroll
        for (int rg = 0; rg < 4; ++rg) {
          const int row = m0 + (wm << 7) + (m << 4) + (lg << 2) + rg;
          float v = acc[m][n][rg] + bv;
          if (RELU) v = fmaxf(v, 0.f);
          Cf[(size_t)row * N + col] = v;
        }
    }
  }
}

// ---------------- V slice of qkv -> vt [B][512][4096] bf16 ----------------
__global__ __launch_bounds__(256) void transpose_v(const bf16* __restrict__ qkv,
                                                   bf16* __restrict__ vt) {
  __shared__ bf16 tile[64][66];
  const int s0 = blockIdx.x * 64, d0 = blockIdx.y * 64, b = blockIdx.z;
  const int t = threadIdx.x;
#pragma unroll
  for (int it = 0; it < 2; ++it) {
    int c = it * 256 + t;
    int r = c >> 3, g = (c & 7) * 8;
    bf16x8 v = *(const bf16x8*)(qkv + ((size_t)b * 4096 + s0 + r) * 1536 + 1024 + d0 + g);
#pragma unroll
    for (int e = 0; e < 8; ++e) tile[g + e][r] = v[e];
  }
  __syncthreads();
#pragma unroll
  for (int it = 0; it < 2; ++it) {
    int c = it * 256 + t;
    int dr = c >> 3, sg = (c & 7) * 8;
    bf16x8 v;
#pragma unroll
    for (int e = 0; e < 8; ++e) v[e] = tile[dr][sg + e];
    *(bf16x8*)(vt + ((size_t)b * 512 + d0 + dr) * 4096 + s0 + sg) = v;
  }
}

// ---------------- local attention ----------------
// grid (64, 8), 512 threads = 8 waves. Wave (rg = w&3, h = w>>2):
//   QK^T: rows rg*16..rg*16+15, score cols [96h, 96h+96) = n-tiles 6h..6h+5.
//   Softmax combined across the h-pair via LDS; rinv folded into P (bf16).
//   PV: wave w computes all 64 rows x dims [w*64, w*64+64) from P_lds and vt.
__global__ __launch_bounds__(512, 4)
void attn_local(const bf16* __restrict__ qkv, const bf16* __restrict__ vt,
                bf16* __restrict__ aout) {
  __shared__ bf16 P[4][16][200];
  __shared__ float xmx[4][2][16];
  __shared__ float xsm[4][2][16];
  const int qb = blockIdx.x, b = blockIdx.y;
  const int t = threadIdx.x, w = t >> 6, l = t & 63;
  const int rg = w & 3, h = w >> 2;
  const int lr = l & 15, lg = l >> 4;

  bool val[6];
#pragma unroll
  for (int n = 0; n < 6; ++n) {
    int gn = 6 * h + n;
    val[n] = ((unsigned)(qb - 1 + (gn >> 2)) < 64u);
  }

  const size_t qrow = (size_t)b * 4096 + qb * 64 + rg * 16;
  const bf16* qp = qkv + (qrow + lr) * 1536 + lg * 8;
  const bf16* kbase = qkv + ((long)b * 4096 + (long)(qb - 1) * 64) * 1536 + 512;

  f32x4 S[6];
#pragma unroll
  for (int n = 0; n < 6; ++n) S[n] = f32x4{0.f, 0.f, 0.f, 0.f};

  for (int kk = 0; kk < 16; ++kk) {
    bf16x8 aq = *(const bf16x8*)(qp + kk * 32);
#pragma unroll
    for (int n = 0; n < 6; ++n) {
      if (!val[n]) continue;
      const int gn = 6 * h + n;
      bf16x8 bk = *(const bf16x8*)(kbase + (size_t)(gn * 16 + lr) * 1536 + kk * 32 + lg * 8);
      S[n] = __builtin_amdgcn_mfma_f32_16x16x32_bf16(aq, bk, S[n], 0, 0, 0);
    }
  }

  const float scale = 0.044194173824159216f;  // 1/sqrt(512)
  float mx[4] = {-3e38f, -3e38f, -3e38f, -3e38f};
#pragma unroll
  for (int n = 0; n < 6; ++n) {
    if (!val[n]) continue;
#pragma unroll
    for (int i = 0; i < 4; ++i) mx[i] = fmaxf(mx[i], S[n][i]);
  }
#pragma unroll
  for (int i = 0; i < 4; ++i) {
    mx[i] = fmaxf(mx[i], __shfl_xor(mx[i], 1));
    mx[i] = fmaxf(mx[i], __shfl_xor(mx[i], 2));
    mx[i] = fmaxf(mx[i], __shfl_xor(mx[i], 4));
    mx[i] = fmaxf(mx[i], __shfl_xor(mx[i], 8));
  }
  if (lr == 0) {
#pragma unroll
    for (int i = 0; i < 4; ++i) xmx[rg][h][lg * 4 + i] = mx[i];
  }
  __syncthreads();
  float m4[4];
#pragma unroll
  for (int i = 0; i < 4; ++i) m4[i] = fmaxf(mx[i], xmx[rg][h ^ 1][lg * 4 + i]);

  float sm[4] = {0.f, 0.f, 0.f, 0.f};
#pragma unroll
  for (int n = 0; n < 6; ++n) {
    if (!val[n]) continue;
#pragma unroll
    for (int i = 0; i < 4; ++i) {
      float p = __expf((S[n][i] - m4[i]) * scale);
      S[n][i] = p;
      sm[i] += p;
    }
  }
#pragma unroll
  for (int i = 0; i < 4; ++i) {
    sm[i] += __shfl_xor(sm[i], 1);
    sm[i] += __shfl_xor(sm[i], 2);
    sm[i] += __shfl_xor(sm[i], 4);
    sm[i] += __shfl_xor(sm[i], 8);
  }
  if (lr == 0) {
#pragma unroll
    for (int i = 0; i < 4; ++i) xsm[rg][h][lg * 4 + i] = sm[i];
  }
  __syncthreads();
  float rinv[4];
#pragma unroll
  for (int i = 0; i < 4; ++i) rinv[i] = 1.f / (sm[i] + xsm[rg][h ^ 1][lg * 4 + i]);

#pragma unroll
  for (int n = 0; n < 6; ++n) {
    const int gn = 6 * h + n;
#pragma unroll
    for (int i = 0; i < 4; ++i)
      P[rg][lg * 4 + i][gn * 16 + lr] = val[n] ? (bf16)(S[n][i] * rinv[i]) : (bf16)0.f;
  }
  __syncthreads();

  // PV: dims [w*64, w*64+64), all 64 rows
  f32x4 O[4][4];
#pragma unroll
  for (int rt = 0; rt < 4; ++rt)
#pragma unroll
    for (int dt = 0; dt < 4; ++dt) O[rt][dt] = f32x4{0.f, 0.f, 0.f, 0.f};

  const bf16* vtb = vt + ((long)b * 512 + w * 64) * 4096 + (long)(qb - 1) * 64;
#pragma unroll
  for (int ks = 0; ks < 6; ++ks) {
    if ((unsigned)(qb - 1 + (ks >> 1)) >= 64u) continue;
    bf16x8 vf[4];
#pragma unroll
    for (int dt = 0; dt < 4; ++dt)
      vf[dt] = *(const bf16x8*)(vtb + (size_t)(dt * 16 + lr) * 4096 + ks * 32 + lg * 8);
#pragma unroll
    for (int rt = 0; rt < 4; ++rt) {
      bf16x8 pa = *(const bf16x8*)&P[rt][lr][ks * 32 + lg * 8];
#pragma unroll
      for (int dt = 0; dt < 4; ++dt)
        O[rt][dt] = __builtin_amdgcn_mfma_f32_16x16x32_bf16(pa, vf[dt], O[rt][dt], 0, 0, 0);
    }
  }

  const size_t orow = (size_t)b * 4096 + qb * 64;
#pragma unroll
  for (int rt = 0; rt < 4; ++rt)
#pragma unroll
    for (int dt = 0; dt < 4; ++dt)
#pragma unroll
      for (int i = 0; i < 4; ++i)
        aout[(orow + rt * 16 + lg * 4 + i) * 512 + w * 64 + dt * 16 + lr] =
            (bf16)O[rt][dt][i];
}

// ---------------- LN1: out1 = LN(x + a) -> bf16 ----------------
__global__ __launch_bounds__(256) void ln_res1(const float* __restrict__ x,
                                               const bf16* __restrict__ a,
                                               const float* __restrict__ g,
                                               const float* __restrict__ be,
                                               bf16* __restrict__ out) {
  const int t = threadIdx.x, w = t >> 6, l = t & 63;
  const size_t row = (size_t)blockIdx.x * 4 + w;
  const float* xp = x + row * 512 + l * 8;
  float4 x0 = ((const float4*)xp)[0];
  float4 x1 = ((const float4*)xp)[1];
  bf16x8 av = *(const bf16x8*)(a + row * 512 + l * 8);
  float s[8] = {x0.x + (float)av[0], x0.y + (float)av[1], x0.z + (float)av[2], x0.w + (float)av[3],
                x1.x + (float)av[4], x1.y + (float)av[5], x1.z + (float)av[6], x1.w + (float)av[7]};
  float sum = 0.f;
#pragma unroll
  for (int i = 0; i < 8; ++i) sum += s[i];
#pragma unroll
  for (int m = 1; m <= 32; m <<= 1) sum += __shfl_xor(sum, m);
  const float mean = sum * (1.f / 512.f);
  float vs = 0.f;
#pragma unroll
  for (int i = 0; i < 8; ++i) { float d = s[i] - mean; vs += d * d; }
#pragma unroll
  for (int m = 1; m <= 32; m <<= 1) vs += __shfl_xor(vs, m);
  const float r = rsqrtf(vs * (1.f / 512.f) + 1e-6f);
  float4 g0 = ((const float4*)(g + l * 8))[0], g1 = ((const float4*)(g + l * 8))[1];
  float4 b0 = ((const float4*)(be + l * 8))[0], b1 = ((const float4*)(be + l * 8))[1];
  bf16x8 o;
  o[0] = (bf16)(g0.x * (s[0] - mean) * r + b0.x);
  o[1] = (bf16)(g0.y * (s[1] - mean) * r + b0.y);
  o[2] = (bf16)(g0.z * (s[2] - mean) * r + b0.z);
  o[3] = (bf16)(g0.w * (s[3] - mean) * r + b0.w);
  o[4] = (bf16)(g1.x * (s[4] - mean) * r + b1.x);
  o[5] = (bf16)(g1.y * (s[5] - mean) * r + b1.y);
  o[6] = (bf16)(g1.z * (s[6] - mean) * r + b1.z);
  o[7] = (bf16)(g1.w * (s[7] - mean) * r + b1.w);
  *(bf16x8*)(out + row * 512 + l * 8) = o;
}

// ---------------- LN2: out = LN(out1 + y), y in d_out (f32), in-place ----------------
__global__ __launch_bounds__(256) void ln_res2(const bf16* __restrict__ o1,
                                               float* __restrict__ y,
                                               const float* __restrict__ g,
                                               const float* __restrict__ be) {
  const int t = threadIdx.x, w = t >> 6, l = t & 63;
  const size_t row = (size_t)blockIdx.x * 4 + w;
  float* yp = y + row * 512 + l * 8;
  float4 y0 = ((const float4*)yp)[0];
  float4 y1 = ((const float4*)yp)[1];
  bf16x8 ov = *(const bf16x8*)(o1 + row * 512 + l * 8);
  float s[8] = {y0.x + (float)ov[0], y0.y + (float)ov[1], y0.z + (float)ov[2], y0.w + (float)ov[3],
                y1.x + (float)ov[4], y1.y + (float)ov[5], y1.z + (float)ov[6], y1.w + (float)ov[7]};
  float sum = 0.f;
#pragma unroll
  for (int i = 0; i < 8; ++i) sum += s[i];
#pragma unroll
  for (int m = 1; m <= 32; m <<= 1) sum += __shfl_xor(sum, m);
  const float mean = sum * (1.f / 512.f);
  float vs = 0.f;
#pragma unroll
  for (int i = 0; i < 8; ++i) { float d = s[i] - mean; vs += d * d; }
#pragma unroll
  for (int m = 1; m <= 32; m <<= 1) vs += __shfl_xor(vs, m);
  const float r = rsqrtf(vs * (1.f / 512.f) + 1e-6f);
  float4 g0 = ((const float4*)(g + l * 8))[0], g1 = ((const float4*)(g + l * 8))[1];
  float4 b0 = ((const float4*)(be + l * 8))[0], b1 = ((const float4*)(be + l * 8))[1];
  float4 r0, r1;
  r0.x = g0.x * (s[0] - mean) * r + b0.x;
  r0.y = g0.y * (s[1] - mean) * r + b0.y;
  r0.z = g0.z * (s[2] - mean) * r + b0.z;
  r0.w = g0.w * (s[3] - mean) * r + b0.w;
  r1.x = g1.x * (s[4] - mean) * r + b1.x;
  r1.y = g1.y * (s[5] - mean) * r + b1.y;
  r1.z = g1.z * (s[6] - mean) * r + b1.z;
  r1.w = g1.w * (s[7] - mean) * r + b1.w;
  ((float4*)yp)[0] = r0;
  ((float4*)yp)[1] = r1;
}

extern "C" void kernel_launch(void* const* d_in, const int* in_sizes, int n_in,
                              void* d_out, int out_size, void* d_ws, size_t ws_size,
                              hipStream_t stream) {
  const float* x   = (const float*)d_in[0];
  const float* Wq  = (const float*)d_in[1];
  const float* bq  = (const float*)d_in[2];
  const float* Wk  = (const float*)d_in[3];
  const float* bk  = (const float*)d_in[4];
  const float* Wv  = (const float*)d_in[5];
  const float* bv  = (const float*)d_in[6];
  const float* W1  = (const float*)d_in[7];
  const float* b1  = (const float*)d_in[8];
  const float* W2  = (const float*)d_in[9];
  const float* b2  = (const float*)d_in[10];
  const float* g1  = (const float*)d_in[11];
  const float* be1 = (const float*)d_in[12];
  const float* g2  = (const float*)d_in[13];
  const float* be2 = (const float*)d_in[14];
  float* out = (float*)d_out;

  char* ws = (char*)d_ws;
  bf16*  WqkvT = (bf16*)(ws + 0);          // [1536][512]      1,572,864
  bf16*  W1T   = (bf16*)(ws + 1572864);    // [2048][512]      2,097,152
  bf16*  W2T   = (bf16*)(ws + 3670016);    // [512][2048]      2,097,152
  float* bqkv  = (float*)(ws + 5767168);   // [1536]           6,144
  bf16*  xb    = (bf16*)(ws + 6291456);    // [32768][512]     33,554,432  (reused as attn out)
  bf16*  out1  = (bf16*)(ws + 39845888);   // [32768][512]     33,554,432
  bf16*  qkv   = (bf16*)(ws + 73400320);   // [32768][1536]    100,663,296
  bf16*  vtb   = (bf16*)(ws + 174063616);  // [8][512][4096]   33,554,432  -> end 207,618,048
  bf16*  a_    = xb;
  bf16*  h     = qkv;  // h [32768][2048] reuses qkv+vtb (both dead by FFN1)

  cast_to_bf16<<<8192, 256, 0, stream>>>(x, xb, 2097152);
  transpose_cast<<<dim3(8, 8), 256, 0, stream>>>(Wq, WqkvT, 512, 512);
  transpose_cast<<<dim3(8, 8), 256, 0, stream>>>(Wk, WqkvT + 262144, 512, 512);
  transpose_cast<<<dim3(8, 8), 256, 0, stream>>>(Wv, WqkvT + 524288, 512, 512);
  transpose_cast<<<dim3(32, 8), 256, 0, stream>>>(W1, W1T, 512, 2048);
  transpose_cast<<<dim3(8, 32), 256, 0, stream>>>(W2, W2T, 2048, 512);
  concat_bias<<<6, 256, 0, stream>>>(bq, bk, bv, bqkv);

  gemm256<0, 0><<<dim3(128, 6), 512, 0, stream>>>(xb, WqkvT, bqkv, qkv, 32768, 1536, 512);
  transpose_v<<<dim3(64, 8, 8), 256, 0, stream>>>(qkv, vtb);
  attn_local<<<dim3(64, 8), 512, 0, stream>>>(qkv, vtb, a_);
  ln_res1<<<8192, 256, 0, stream>>>(x, a_, g1, be1, out1);
  gemm256<1, 0><<<dim3(128, 8), 512, 0, stream>>>(out1, W1T, b1, h, 32768, 2048, 512);
  gemm256<0, 1><<<dim3(128, 2), 512, 0, stream>>>(h, W2T, b2, out, 32768, 512, 2048);
  ln_res2<<<8192, 256, 0, stream>>>(out1, out, g2, be2);
}